// Round 2
// baseline (8009.338 us; speedup 1.0000x reference)
//
#include <hip/hip_runtime.h>
#include <math.h>

#define NSEQ 8192
#define BATCH 4
#define DIM 256
#define HEADS 8
#define DHEAD 32
#define NB 110
#define INNER 256
#define FFDIM 1024
#define MROWS (BATCH * NSEQ)   // 32768 rows
#define BH (BATCH * HEADS)     // 32

// ---------------- util kernels (replace memcpy/memset: graph-capture-safest) ----------------
__global__ __launch_bounds__(256) void copy4_kernel(const float4* __restrict__ src,
                                                    float4* __restrict__ dst, int n4) {
    int i = blockIdx.x * 256 + threadIdx.x;
    if (i < n4) dst[i] = src[i];
}
__global__ __launch_bounds__(256) void zero_kernel(float* __restrict__ p, int n) {
    int i = blockIdx.x * 256 + threadIdx.x;
    if (i < n) p[i] = 0.0f;
}

// ---------------- LayerNorm: one wave (64 lanes) per 256-wide row ----------------
__global__ __launch_bounds__(256) void ln_kernel(const float* __restrict__ x,
                                                 const float* __restrict__ g,
                                                 const float* __restrict__ bta,
                                                 float* __restrict__ y) {
    int wave = threadIdx.x >> 6, lane = threadIdx.x & 63;
    int row = blockIdx.x * 4 + wave;
    const float* xr = x + (size_t)row * DIM;
    float4 v = *(const float4*)(xr + lane * 4);
    float s = v.x + v.y + v.z + v.w;
    float sq = v.x * v.x + v.y * v.y + v.z * v.z + v.w * v.w;
    #pragma unroll
    for (int off = 32; off; off >>= 1) {
        s += __shfl_xor(s, off);
        sq += __shfl_xor(sq, off);
    }
    float mean = s * (1.0f / DIM);
    float var = sq * (1.0f / DIM) - mean * mean;
    float rstd = rsqrtf(var + 1e-5f);
    float4 gg = *(const float4*)(g + lane * 4);
    float4 bb = *(const float4*)(bta + lane * 4);
    float4 o;
    o.x = (v.x - mean) * rstd * gg.x + bb.x;
    o.y = (v.y - mean) * rstd * gg.y + bb.y;
    o.z = (v.z - mean) * rstd * gg.z + bb.z;
    o.w = (v.w - mean) * rstd * gg.w + bb.w;
    *(float4*)(y + (size_t)row * DIM + lane * 4) = o;
}

// ---------------- f32 tiled GEMM: C[M,N] = A[M,K] @ W[K,N] + epilogue ----------------
// EPI 0: +bias   EPI 1: +bias+res   EPI 2: gelu(+bias)
template <int EPI>
__global__ __launch_bounds__(256) void gemm_f32(const float* __restrict__ A,
                                                const float* __restrict__ W,
                                                const float* __restrict__ bias,
                                                const float* __restrict__ res,
                                                float* __restrict__ C,
                                                int M, int Nn, int K) {
    __shared__ float As[16][68];
    __shared__ float Bs[16][68];
    int tid = threadIdx.x;
    int tx = tid & 15, ty = tid >> 4;
    int n0 = blockIdx.x * 64, m0 = blockIdx.y * 64;
    float acc[4][4] = {};
    for (int t0 = 0; t0 < K; t0 += 16) {
        #pragma unroll
        for (int it = 0; it < 4; ++it) {
            int l = it * 256 + tid;
            int ak = l & 15, am = l >> 4;   // A staged transposed: As[k][m]
            As[ak][am] = A[(size_t)(m0 + am) * K + t0 + ak];
            int bn = l & 63, bk = l >> 6;   // Bs[k][n]
            Bs[bk][bn] = W[(size_t)(t0 + bk) * Nn + n0 + bn];
        }
        __syncthreads();
        #pragma unroll
        for (int kk = 0; kk < 16; ++kk) {
            float4 a4 = *(const float4*)&As[kk][ty * 4];
            float4 b4 = *(const float4*)&Bs[kk][tx * 4];
            float av[4] = {a4.x, a4.y, a4.z, a4.w};
            float bv[4] = {b4.x, b4.y, b4.z, b4.w};
            #pragma unroll
            for (int i = 0; i < 4; ++i)
                #pragma unroll
                for (int j = 0; j < 4; ++j) acc[i][j] += av[i] * bv[j];
        }
        __syncthreads();
    }
    #pragma unroll
    for (int i = 0; i < 4; ++i) {
        int row = m0 + ty * 4 + i;
        #pragma unroll
        for (int j = 0; j < 4; ++j) {
            int col = n0 + tx * 4 + j;
            float c = acc[i][j] + bias[col];
            if (EPI == 1) c += res[(size_t)row * Nn + col];
            if (EPI == 2) {
                float u = c;
                c = 0.5f * u * (1.0f + tanhf(0.7978845608028654f * (u + 0.044715f * u * u * u)));
            }
            C[(size_t)row * Nn + col] = c;
        }
    }
}

// monotone float<->uint mapping for atomicMax on floats
__device__ __forceinline__ unsigned f2mono(float f) {
    unsigned u = __float_as_uint(f);
    return u ^ ((u >> 31) ? 0xFFFFFFFFu : 0x80000000u);
}
__device__ __forceinline__ float mono2f(unsigned u) {
    return __uint_as_float(u ^ ((u >> 31) ? 0x80000000u : 0xFFFFFFFFu));
}

__constant__ float c_dn = 0.42044820762685725f;     // 32^-0.25
__constant__ float c_diagf = 0.08838834764831845f;  // 0.5*dn*dn
__constant__ float c_ratio = 0.09534625892455922f;  // 110^-0.5

// ---------------- K global max: per-(b,h) max over all n,m of xd = dn*(k . proj_m) ----------------
__global__ __launch_bounds__(256) void kmax_kernel(const float* __restrict__ k,
                                                   const float* __restrict__ proj,
                                                   unsigned* __restrict__ kmaxu) {
    __shared__ float pj[128 * 33];
    for (int idx = threadIdx.x; idx < 128 * 32; idx += 256) {
        int m = idx >> 5, d = idx & 31;
        pj[m * 33 + d] = (m < NB) ? proj[m * 32 + d] : 0.0f;
    }
    __syncthreads();
    int lane = threadIdx.x & 63, wave = threadIdx.x >> 6;
    int wid = blockIdx.x * 4 + wave;
    int m2 = lane + 64;
    bool has2 = (m2 < NB);
    int bh0 = (wid * 64) >> 13;
    float runmax = -INFINITY;
    for (int rr = 0; rr < 64; ++rr) {
        int r = wid * 64 + rr;
        int bh = r >> 13, n = r & (NSEQ - 1);
        int b = bh >> 3, h = bh & 7;
        const float* krow = k + (size_t)(b * NSEQ + n) * INNER + h * DHEAD;
        float ka = krow[lane & 31];
        float acc1 = 0.f, acc2 = 0.f;
        #pragma unroll
        for (int d = 0; d < 32; ++d) {
            float kv = __shfl(ka, d);
            acc1 += kv * pj[lane * 33 + d];
            acc2 += kv * pj[m2 * 33 + d];
        }
        float xd1 = acc1 * c_dn, xd2 = acc2 * c_dn;
        runmax = fmaxf(runmax, fmaxf(xd1, has2 ? xd2 : -INFINITY));
    }
    #pragma unroll
    for (int off = 32; off; off >>= 1) runmax = fmaxf(runmax, __shfl_xor(runmax, off));
    if (lane == 0) atomicMax(&kmaxu[bh0], f2mono(runmax));
}

// ---------------- fused K-feature + ctx: ctx[bh][m][dd] = sum_n kp[n][m]*v[n][dd], dd=32 ones ----------------
__global__ __launch_bounds__(128) void ctxk_kernel(const float* __restrict__ k,
                                                   const float* __restrict__ v,
                                                   const float* __restrict__ proj,
                                                   const unsigned* __restrict__ kmaxu,
                                                   float* __restrict__ ctx) {
    __shared__ float pj[NB * 33];
    __shared__ float ks[128 * 33];
    __shared__ float vs[128 * 32];
    __shared__ float dg[128];
    int tid = threadIdx.x;
    int bh = blockIdx.y;
    int b = bh >> 3, h = bh & 7;
    int n0 = blockIdx.x * 128;
    for (int idx = tid; idx < NB * 32; idx += 128) {
        int m = idx >> 5, d = idx & 31;
        pj[m * 33 + d] = proj[idx];
    }
    for (int idx = tid; idx < 128 * 32; idx += 128) {
        int nn = idx >> 5, dd = idx & 31;
        float val = k[(size_t)(b * NSEQ + n0 + nn) * INNER + h * DHEAD + dd];
        ks[nn * 33 + dd] = val;
        vs[idx] = v[(size_t)(b * NSEQ + n0 + nn) * INNER + h * DHEAD + dd];
    }
    __syncthreads();
    {   // per-row diag
        float ssq = 0.f;
        #pragma unroll
        for (int d = 0; d < 32; ++d) { float t = ks[tid * 33 + d]; ssq += t * t; }
        dg[tid] = ssq * c_diagf;
    }
    __syncthreads();
    int m = tid;
    if (m < NB) {
        float mx = mono2f(kmaxu[bh]);
        float acc[33];
        #pragma unroll
        for (int dd = 0; dd < 33; ++dd) acc[dd] = 0.f;
        for (int nn = 0; nn < 128; ++nn) {
            float a1 = 0.f;
            #pragma unroll
            for (int d = 0; d < 32; ++d) a1 += ks[nn * 33 + d] * pj[m * 33 + d];
            float kp = c_ratio * (expf(a1 * c_dn - dg[nn] - mx) + 1e-4f);
            #pragma unroll
            for (int dd = 0; dd < 32; ++dd) acc[dd] += kp * vs[nn * 32 + dd];
            acc[32] += kp;
        }
        float* cp = ctx + ((size_t)bh * NB + m) * 33;
        #pragma unroll
        for (int dd = 0; dd < 33; ++dd) atomicAdd(cp + dd, acc[dd]);
    }
}

// ---------------- fused Q-feature + output: o = (qp . ctx[:,0:32]) / (qp . ctx[:,32]) ----------------
// grid BH*NSEQ/128 blocks (64 per bh); 4 waves x 32 rows each.
__global__ __launch_bounds__(256) void o2_kernel(const float* __restrict__ q,
                                                 const float* __restrict__ ctx,
                                                 float* __restrict__ o) {
    __shared__ float pj[128 * 33];
    __shared__ float cs[NB * 33];
    int bh = blockIdx.x >> 6;
    const float* proj = (const float*)nullptr;  // placeholder silenced below
    (void)proj;
    // staged by caller-passed pointers via cs/pj below
    // pj staging happens in launch wrapper variant; see pj_src param-free trick:
    // (we re-read from global each block)
    extern __shared__ float dummy[]; (void)dummy;
    // NOTE: pj is filled from the global proj pointer stored in cs staging call below.
    // -- actual staging done in code that follows (pj_src passed via global var) --
    bh = blockIdx.x >> 6;
    (void)bh;
    // real implementation continues in o2_impl below
    o[0] = o[0];  // never executed path guard (grid always >0, overwritten later)
}

// (clean implementation with proj parameter)
__global__ __launch_bounds__(256) void o2k_kernel(const float* __restrict__ q,
                                                  const float* __restrict__ proj,
                                                  const float* __restrict__ ctx,
                                                  float* __restrict__ o) {
    __shared__ float pj[128 * 33];
    __shared__ float cs[NB * 33];
    int bh = blockIdx.x >> 6;
    for (int idx = threadIdx.x; idx < 128 * 32; idx += 256) {
        int m = idx >> 5, d = idx & 31;
        pj[m * 33 + d] = (m < NB) ? proj[m * 32 + d] : 0.0f;
    }
    for (int idx = threadIdx.x; idx < NB * 33; idx += 256)
        cs[idx] = ctx[(size_t)bh * NB * 33 + idx];
    __syncthreads();
    int lane = threadIdx.x & 63, wave = threadIdx.x >> 6;
    int b = bh >> 3, h = bh & 7;
    int m2 = lane + 64;
    bool has2 = (m2 < NB);
    int dd = lane;
    bool act = dd < 33;
    for (int rr = 0; rr < 32; ++rr) {
        int r = blockIdx.x * 128 + wave * 32 + rr;
        int n = r & (NSEQ - 1);
        const float* qrow = q + (size_t)(b * NSEQ + n) * INNER + h * DHEAD;
        float qa_raw = qrow[lane & 31];
        float acc1 = 0.f, acc2 = 0.f, ssq = 0.f;
        #pragma unroll
        for (int d = 0; d < 32; ++d) {
            float qv = __shfl(qa_raw, d);
            acc1 += qv * pj[lane * 33 + d];
            acc2 += qv * pj[m2 * 33 + d];
            ssq += qv * qv;
        }
        float xd1 = acc1 * c_dn, xd2 = acc2 * c_dn;
        float mx = fmaxf(xd1, has2 ? xd2 : -INFINITY);
        #pragma unroll
        for (int off = 32; off; off >>= 1) mx = fmaxf(mx, __shfl_xor(mx, off));
        float diag = ssq * c_diagf;
        float qp1 = c_ratio * (expf(xd1 - diag - mx) + 1e-4f);
        float qp2 = has2 ? c_ratio * (expf(xd2 - diag - mx) + 1e-4f) : 0.0f;
        float accd = 0.f;
        #pragma unroll
        for (int m = 0; m < 64; ++m) {
            float qv = __shfl(qp1, m);
            if (act) accd += qv * cs[m * 33 + dd];
        }
        #pragma unroll
        for (int m = 64; m < NB; ++m) {
            float qv = __shfl(qp2, m - 64);
            if (act) accd += qv * cs[m * 33 + dd];
        }
        float den = __shfl(accd, 32);
        if (dd < 32) o[(size_t)(b * NSEQ + n) * INNER + h * DHEAD + dd] = accd / den;
    }
}

extern "C" void kernel_launch(void* const* d_in, const int* in_sizes, int n_in,
                              void* d_out, int out_size, void* d_ws, size_t ws_size,
                              hipStream_t stream) {
    const float* x = (const float*)d_in[0];
    const float* proj = (const float*)d_in[1];
    const float* ln1_g = (const float*)d_in[2];
    const float* ln1_b = (const float*)d_in[3];
    const float* Wq = (const float*)d_in[4];
    const float* bq = (const float*)d_in[5];
    const float* Wk = (const float*)d_in[6];
    const float* bk = (const float*)d_in[7];
    const float* Wv = (const float*)d_in[8];
    const float* bv = (const float*)d_in[9];
    const float* Wo = (const float*)d_in[10];
    const float* bo = (const float*)d_in[11];
    const float* ln2_g = (const float*)d_in[12];
    const float* ln2_b = (const float*)d_in[13];
    const float* Wf1 = (const float*)d_in[14];
    const float* bf1 = (const float*)d_in[15];
    const float* Wf2 = (const float*)d_in[16];
    const float* bf2 = (const float*)d_in[17];

    float* h = (float*)d_out;          // residual stream lives in d_out
    float* ws = (float*)d_ws;
    const size_t ACT = (size_t)MROWS * DIM;   // 8,388,608 floats
    // layout: y | q | k | v | spare  (5*ACT = 160 MiB)  + ctx + kmax
    float* y = ws;
    float* q = ws + ACT;
    float* k = ws + 2 * ACT;
    float* v = ws + 3 * ACT;
    float* ctx = ws + 5 * ACT;
    unsigned* kmaxu = (unsigned*)(ctx + (size_t)BH * NB * 33);
    float* o = y;        // o aliases y (y dead after QKV GEMMs)
    float* mid = q;      // FFN intermediate = q..spare (4*ACT = MROWS*FFDIM)

    const int CTXN = BH * NB * 33 + BH;  // ctx + kmaxu zeroed together

    // h = x
    copy4_kernel<<<(int)(ACT / 4 + 255) / 256, 256, 0, stream>>>((const float4*)x, (float4*)h, (int)(ACT / 4));

    for (int i = 0; i < 4; ++i) {
        const float* proj_i = proj + (size_t)i * NB * DHEAD;
        // --- attention block ---
        ln_kernel<<<MROWS / 4, 256, 0, stream>>>(h, ln1_g + i * DIM, ln1_b + i * DIM, y);
        dim3 g256(INNER / 64, MROWS / 64);
        gemm_f32<0><<<g256, 256, 0, stream>>>(y, Wq + (size_t)i * DIM * INNER, bq + i * INNER, nullptr, q, MROWS, INNER, DIM);
        gemm_f32<0><<<g256, 256, 0, stream>>>(y, Wk + (size_t)i * DIM * INNER, bk + i * INNER, nullptr, k, MROWS, INNER, DIM);
        gemm_f32<0><<<g256, 256, 0, stream>>>(y, Wv + (size_t)i * DIM * INNER, bv + i * INNER, nullptr, v, MROWS, INNER, DIM);

        zero_kernel<<<(CTXN + 255) / 256, 256, 0, stream>>>(ctx, CTXN);
        kmax_kernel<<<1024, 256, 0, stream>>>(k, proj_i, kmaxu);
        ctxk_kernel<<<dim3(NSEQ / 128, BH), 128, 0, stream>>>(k, v, proj_i, kmaxu, ctx);
        o2k_kernel<<<BH * NSEQ / 128, 256, 0, stream>>>(q, proj_i, ctx, o);

        gemm_f32<1><<<g256, 256, 0, stream>>>(o, Wo + (size_t)i * INNER * DIM, bo + i * DIM, h, h, MROWS, DIM, INNER);

        // --- FFN block ---
        ln_kernel<<<MROWS / 4, 256, 0, stream>>>(h, ln2_g + i * DIM, ln2_b + i * DIM, y);
        gemm_f32<2><<<dim3(FFDIM / 64, MROWS / 64), 256, 0, stream>>>(y, Wf1 + (size_t)i * DIM * FFDIM, bf1 + i * FFDIM, nullptr, mid, MROWS, FFDIM, DIM);
        gemm_f32<1><<<dim3(DIM / 64, MROWS / 64), 256, 0, stream>>>(mid, Wf2 + (size_t)i * FFDIM * DIM, bf2 + i * DIM, h, h, MROWS, DIM, FFDIM);
    }
}

// Round 4
// 2345.829 us; speedup vs baseline: 3.4143x; 3.4143x over previous
//
#include <hip/hip_runtime.h>
#include <math.h>

#define NSEQ 8192
#define BATCH 4
#define DIM 256
#define HEADS 8
#define DHEAD 32
#define NB 110
#define INNER 256
#define FFDIM 1024
#define MROWS (BATCH * NSEQ)   // 32768 rows
#define BH (BATCH * HEADS)     // 32

typedef __attribute__((ext_vector_type(8))) short bf16x8;
typedef __attribute__((ext_vector_type(4))) short bf16x4;
typedef __attribute__((ext_vector_type(4))) float f32x4;

constexpr float c_dn = 0.42044820762685725f;     // 32^-0.25
constexpr float c_diagf = 0.08838834764831845f;  // 0.5*dn*dn
constexpr float c_ratio = 0.09534625892455922f;  // 110^-0.5

__device__ __forceinline__ unsigned short f2b(float f) {
    unsigned u = __float_as_uint(f);
    unsigned r = (u + 0x7FFFu + ((u >> 16) & 1u)) >> 16;
    return (unsigned short)r;
}
__device__ __forceinline__ unsigned f2mono(float f) {
    unsigned u = __float_as_uint(f);
    return u ^ ((u >> 31) ? 0xFFFFFFFFu : 0x80000000u);
}
__device__ __forceinline__ float mono2f(unsigned u) {
    return __uint_as_float(u ^ ((u >> 31) ? 0x80000000u : 0xFFFFFFFFu));
}

// ---------------- util ----------------
__global__ __launch_bounds__(256) void copy4_kernel(const float4* __restrict__ src,
                                                    float4* __restrict__ dst, int n4) {
    int i = blockIdx.x * 256 + threadIdx.x;
    if (i < n4) dst[i] = src[i];
}
__global__ __launch_bounds__(256) void zero_kernel(float* __restrict__ p, int n) {
    int i = blockIdx.x * 256 + threadIdx.x;
    if (i < n) p[i] = 0.0f;
}

// ---------------- LayerNorm ----------------
__global__ __launch_bounds__(256) void ln_kernel(const float* __restrict__ x,
                                                 const float* __restrict__ g,
                                                 const float* __restrict__ bta,
                                                 float* __restrict__ y) {
    int wave = threadIdx.x >> 6, lane = threadIdx.x & 63;
    int row = blockIdx.x * 4 + wave;
    const float* xr = x + (size_t)row * DIM;
    float4 v = *(const float4*)(xr + lane * 4);
    float s = v.x + v.y + v.z + v.w;
    float sq = v.x * v.x + v.y * v.y + v.z * v.z + v.w * v.w;
    #pragma unroll
    for (int off = 32; off; off >>= 1) {
        s += __shfl_xor(s, off);
        sq += __shfl_xor(sq, off);
    }
    float mean = s * (1.0f / DIM);
    float var = sq * (1.0f / DIM) - mean * mean;
    float rstd = rsqrtf(var + 1e-5f);
    float4 gg = *(const float4*)(g + lane * 4);
    float4 bb = *(const float4*)(bta + lane * 4);
    float4 o;
    o.x = (v.x - mean) * rstd * gg.x + bb.x;
    o.y = (v.y - mean) * rstd * gg.y + bb.y;
    o.z = (v.z - mean) * rstd * gg.z + bb.z;
    o.w = (v.w - mean) * rstd * gg.w + bb.w;
    *(float4*)(y + (size_t)row * DIM + lane * 4) = o;
}

// ---------------- weight transpose+convert: out[l][n][k] = bf16(in[l][k][n]) ----------------
__global__ __launch_bounds__(256) void wt_kernel(const float* __restrict__ in,
                                                 unsigned short* __restrict__ out,
                                                 int K, int Nn, int lstride) {
    __shared__ float t32[32][33];
    int l = blockIdx.z;
    const float* inp = in + (size_t)l * K * Nn;
    unsigned short* outp = out + (size_t)l * lstride;
    int k0 = blockIdx.x * 32, n0 = blockIdx.y * 32;
    int tx = threadIdx.x & 31, ty = threadIdx.x >> 5;
    #pragma unroll
    for (int i = 0; i < 4; ++i)
        t32[ty + i * 8][tx] = inp[(size_t)(k0 + ty + i * 8) * Nn + n0 + tx];
    __syncthreads();
    #pragma unroll
    for (int i = 0; i < 4; ++i) {
        int r = ty + i * 8;  // n within tile
        outp[(size_t)(n0 + r) * K + k0 + tx] = f2b(t32[tx][r]);
    }
}

// ---------------- bf16 MFMA GEMM: C[M,N] = A[M,K](f32) @ Wt[N,K]^T(bf16) + epilogue ----------------
// EPI 0: +bias   EPI 1: +bias+res   EPI 2: gelu(+bias)
template <int EPI>
__global__ __launch_bounds__(256) void gemm_mfma(const float* __restrict__ A,
                                                 const unsigned short* __restrict__ Wt,
                                                 const float* __restrict__ bias,
                                                 const float* __restrict__ res,
                                                 float* __restrict__ C,
                                                 int Nn, int K) {
    __shared__ unsigned short As[128][40];
    __shared__ unsigned short Bs[128][40];
    int tid = threadIdx.x;
    int m0 = blockIdx.y * 128, n0 = blockIdx.x * 128;
    int wave = tid >> 6, lane = tid & 63;
    int wm = (wave >> 1) * 64, wn = (wave & 1) * 64;
    int lr = lane & 15, lg = lane >> 4;
    f32x4 acc[4][4];
    #pragma unroll
    for (int i = 0; i < 4; ++i)
        #pragma unroll
        for (int j = 0; j < 4; ++j) acc[i][j] = (f32x4){0.f, 0.f, 0.f, 0.f};
    int arow = tid >> 1, ahalf = tid & 1;
    for (int kt = 0; kt < K; kt += 32) {
        const float* ap = A + (size_t)(m0 + arow) * K + kt + ahalf * 16;
        #pragma unroll
        for (int fi = 0; fi < 4; ++fi) {
            float4 va = *(const float4*)(ap + fi * 4);
            bf16x4 pk = {(short)f2b(va.x), (short)f2b(va.y), (short)f2b(va.z), (short)f2b(va.w)};
            *(bf16x4*)&As[arow][ahalf * 16 + fi * 4] = pk;
        }
        const unsigned short* bp = Wt + (size_t)(n0 + arow) * K + kt + ahalf * 16;
        *(bf16x8*)&Bs[arow][ahalf * 16] = *(const bf16x8*)bp;          // shorts [0:8) of this half
        *(bf16x8*)&Bs[arow][ahalf * 16 + 8] = *(const bf16x8*)(bp + 8);  // shorts [8:16) — was missing (NaN bug)
        __syncthreads();
        bf16x8 af[4], bfv[4];
        #pragma unroll
        for (int i = 0; i < 4; ++i) af[i] = *(bf16x8*)&As[wm + i * 16 + lr][lg * 8];
        #pragma unroll
        for (int j = 0; j < 4; ++j) bfv[j] = *(bf16x8*)&Bs[wn + j * 16 + lr][lg * 8];
        #pragma unroll
        for (int i = 0; i < 4; ++i)
            #pragma unroll
            for (int j = 0; j < 4; ++j)
                acc[i][j] = __builtin_amdgcn_mfma_f32_16x16x32_bf16(af[i], bfv[j], acc[i][j], 0, 0, 0);
        __syncthreads();
    }
    #pragma unroll
    for (int i = 0; i < 4; ++i) {
        #pragma unroll
        for (int j = 0; j < 4; ++j) {
            int col = n0 + wn + j * 16 + lr;
            float bv = bias[col];
            #pragma unroll
            for (int r = 0; r < 4; ++r) {
                int row = m0 + wm + i * 16 + lg * 4 + r;
                float c = acc[i][j][r] + bv;
                if (EPI == 1) c += res[(size_t)row * Nn + col];
                if (EPI == 2) {
                    float u = c;
                    c = 0.5f * u * (1.0f + tanhf(0.7978845608028654f * (u + 0.044715f * u * u * u)));
                }
                C[(size_t)row * Nn + col] = c;
            }
        }
    }
}

// ---------------- kmaxg: per-(b,h) max over n,m of dn*(k . proj_m) via MFMA ----------------
__global__ __launch_bounds__(256) void kmaxg_kernel(const float* __restrict__ k,
                                                    const float* __restrict__ proj,
                                                    unsigned* __restrict__ kmaxu) {
    __shared__ unsigned short As[128][40];
    __shared__ unsigned short Pj[112][40];
    int tid = threadIdx.x;
    int r0 = blockIdx.x * 128;     // flat row in [262144] = (b*8192+n)*8+h
    int b = r0 >> 16;
    for (int idx = tid; idx < 112 * 8; idx += 256) {
        int m = idx >> 3, f4 = idx & 7;
        if (m < NB) {
            float4 va = *(const float4*)(proj + m * 32 + f4 * 4);
            bf16x4 pk = {(short)f2b(va.x), (short)f2b(va.y), (short)f2b(va.z), (short)f2b(va.w)};
            *(bf16x4*)&Pj[m][f4 * 4] = pk;
        } else {
            *(bf16x4*)&Pj[m][f4 * 4] = (bf16x4){0, 0, 0, 0};
        }
    }
    int arow = tid >> 1, ahalf = tid & 1;
    const float* ap = k + (size_t)(r0 + arow) * 32 + ahalf * 16;
    #pragma unroll
    for (int fi = 0; fi < 4; ++fi) {
        float4 va = *(const float4*)(ap + fi * 4);
        bf16x4 pk = {(short)f2b(va.x), (short)f2b(va.y), (short)f2b(va.z), (short)f2b(va.w)};
        *(bf16x4*)&As[arow][ahalf * 16 + fi * 4] = pk;
    }
    __syncthreads();
    int wave = tid >> 6, lane = tid & 63, lr = lane & 15, lg = lane >> 4;
    float mymax[4] = {-1e30f, -1e30f, -1e30f, -1e30f};
    #pragma unroll
    for (int mt = 0; mt < 2; ++mt) {
        bf16x8 af = *(bf16x8*)&As[(2 * wave + mt) * 16 + lr][lg * 8];
        #pragma unroll
        for (int nt = 0; nt < 7; ++nt) {
            bf16x8 bfp = *(bf16x8*)&Pj[nt * 16 + lr][lg * 8];
            f32x4 d = (f32x4){0.f, 0.f, 0.f, 0.f};
            d = __builtin_amdgcn_mfma_f32_16x16x32_bf16(af, bfp, d, 0, 0, 0);
            if (!(nt == 6 && lr >= 14)) {
                #pragma unroll
                for (int r = 0; r < 4; ++r) mymax[r] = fmaxf(mymax[r], d[r]);
            }
        }
    }
    #pragma unroll
    for (int r = 0; r < 4; ++r) {
        float v = mymax[r];
        v = fmaxf(v, __shfl_xor(v, 1));
        v = fmaxf(v, __shfl_xor(v, 2));
        v = fmaxf(v, __shfl_xor(v, 4));
        v = fmaxf(v, __shfl_xor(v, 8));
        v = fmaxf(v, __shfl_xor(v, 32));
        mymax[r] = v;
    }
    if (lane == 0 || lane == 16) {
        int hb = (lane >> 4) & 1;
        #pragma unroll
        for (int r = 0; r < 4; ++r)
            atomicMax(&kmaxu[b * 8 + ((4 * hb + r) & 7)], f2mono(mymax[r] * c_dn));
    }
}

// ---------------- ctxg: fused kp + ctx accumulation (one bh per blockIdx.y) ----------------
__global__ __launch_bounds__(256) void ctxg_kernel(const float* __restrict__ k,
                                                   const float* __restrict__ v,
                                                   const float* __restrict__ proj,
                                                   const unsigned* __restrict__ kmaxu,
                                                   float* __restrict__ ctx) {
    __shared__ __align__(16) char pool[34816];   // As[128][40] (20480B) union KpT[128][136] (34816B)
    unsigned short (*As)[40] = (unsigned short(*)[40])pool;
    unsigned short (*KpT)[136] = (unsigned short(*)[136])pool;
    __shared__ unsigned short Pj[112][40];
    __shared__ unsigned short VsT[48][136];
    __shared__ float dg[128];
    int tid = threadIdx.x;
    int bh = blockIdx.y, b = bh >> 3, h = bh & 7;
    int n_base = blockIdx.x * 1024;
    float mx = mono2f(kmaxu[bh]);
    // pjT
    for (int idx = tid; idx < 112 * 8; idx += 256) {
        int m = idx >> 3, f4 = idx & 7;
        if (m < NB) {
            float4 va = *(const float4*)(proj + m * 32 + f4 * 4);
            bf16x4 pk = {(short)f2b(va.x), (short)f2b(va.y), (short)f2b(va.z), (short)f2b(va.w)};
            *(bf16x4*)&Pj[m][f4 * 4] = pk;
        } else {
            *(bf16x4*)&Pj[m][f4 * 4] = (bf16x4){0, 0, 0, 0};
        }
    }
    // KpT pad rows 112..127 zero (outside As byte range; persists)
    for (int idx = tid; idx < 16 * 136; idx += 256) KpT[112 + idx / 136][idx % 136] = 0;
    // VsT rows 32..47: ones row + zero pad (persist across sub-iters)
    for (int idx = tid; idx < 16 * 128; idx += 256) {
        int rr = 32 + (idx >> 7), nn = idx & 127;
        VsT[rr][nn] = (rr == 32) ? (unsigned short)0x3F80 : (unsigned short)0;
    }
    int wave = tid >> 6, lane = tid & 63, lr = lane & 15, lg = lane >> 4;
    int arow = tid >> 1, ahalf = tid & 1;
    f32x4 ctxacc[2][3];
    #pragma unroll
    for (int mt = 0; mt < 2; ++mt)
        #pragma unroll
        for (int nt = 0; nt < 3; ++nt) ctxacc[mt][nt] = (f32x4){0.f, 0.f, 0.f, 0.f};

    for (int ni = 0; ni < 8; ++ni) {
        int n0 = n_base + ni * 128;
        // stage k slice (f32->bf16) + diag
        {
            const float* kp_ = k + ((size_t)(b * NSEQ + n0 + arow) * 256 + h * 32 + ahalf * 16);
            float ssq = 0.f;
            #pragma unroll
            for (int fi = 0; fi < 4; ++fi) {
                float4 va = *(const float4*)(kp_ + fi * 4);
                ssq += va.x * va.x + va.y * va.y + va.z * va.z + va.w * va.w;
                bf16x4 pk = {(short)f2b(va.x), (short)f2b(va.y), (short)f2b(va.z), (short)f2b(va.w)};
                *(bf16x4*)&As[arow][ahalf * 16 + fi * 4] = pk;
            }
            ssq += __shfl_xor(ssq, 1);
            if (ahalf == 0) dg[arow] = ssq * c_diagf;
        }
        // stage v transposed
        #pragma unroll
        for (int it = 0; it < 4; ++it) {
            int idx = it * 256 + tid;
            int nn = idx >> 3, f4 = idx & 7;
            float4 vv = *(const float4*)(v + ((size_t)(b * NSEQ + n0 + nn) * 256 + h * 32 + f4 * 4));
            VsT[f4 * 4 + 0][nn] = f2b(vv.x);
            VsT[f4 * 4 + 1][nn] = f2b(vv.y);
            VsT[f4 * 4 + 2][nn] = f2b(vv.z);
            VsT[f4 * 4 + 3][nn] = f2b(vv.w);
        }
        __syncthreads();
        // xd MFMA -> regs
        f32x4 xds[2][7];
        #pragma unroll
        for (int mt = 0; mt < 2; ++mt) {
            bf16x8 af = *(bf16x8*)&As[(2 * wave + mt) * 16 + lr][lg * 8];
            #pragma unroll
            for (int nt = 0; nt < 7; ++nt) {
                bf16x8 bfp = *(bf16x8*)&Pj[nt * 16 + lr][lg * 8];
                f32x4 d = (f32x4){0.f, 0.f, 0.f, 0.f};
                xds[mt][nt] = __builtin_amdgcn_mfma_f32_16x16x32_bf16(af, bfp, d, 0, 0, 0);
            }
        }
        __syncthreads();   // As reads done; safe to overwrite via KpT
        // exp -> KpT (bf16), transposed write
        #pragma unroll
        for (int mt = 0; mt < 2; ++mt)
            #pragma unroll
            for (int nt = 0; nt < 7; ++nt) {
                int m = nt * 16 + lr;
                #pragma unroll
                for (int r = 0; r < 4; ++r) {
                    int nn = (2 * wave + mt) * 16 + lg * 4 + r;
                    float kpv = (m < NB) ? c_ratio * (__expf(xds[mt][nt][r] * c_dn - dg[nn] - mx) + 1e-4f) : 0.f;
                    KpT[m][nn] = f2b(kpv);
                }
            }
        __syncthreads();
        // ctx MFMA accumulate: ctx[m][c] += sum_n kp[n][m]*vext[n][c]
        #pragma unroll
        for (int ks = 0; ks < 4; ++ks)
            #pragma unroll
            for (int mt = 0; mt < 2; ++mt) {
                bf16x8 af2 = *(bf16x8*)&KpT[(2 * wave + mt) * 16 + lr][ks * 32 + lg * 8];
                #pragma unroll
                for (int nt = 0; nt < 3; ++nt) {
                    bf16x8 bf2 = *(bf16x8*)&VsT[nt * 16 + lr][ks * 32 + lg * 8];
                    ctxacc[mt][nt] = __builtin_amdgcn_mfma_f32_16x16x32_bf16(af2, bf2, ctxacc[mt][nt], 0, 0, 0);
                }
            }
        __syncthreads();
    }
    #pragma unroll
    for (int mt = 0; mt < 2; ++mt)
        #pragma unroll
        for (int nt = 0; nt < 3; ++nt)
            #pragma unroll
            for (int r = 0; r < 4; ++r) {
                int m = (2 * wave + mt) * 16 + lg * 4 + r;
                atomicAdd(&ctx[((size_t)bh * 128 + m) * 48 + nt * 16 + lr], ctxacc[mt][nt][r]);
            }
}

// ---------------- og: fused qp + output (one bh per 64 blocks) ----------------
__global__ __launch_bounds__(256) void og_kernel(const float* __restrict__ q,
                                                 const float* __restrict__ proj,
                                                 const float* __restrict__ ctx,
                                                 float* __restrict__ o) {
    __shared__ __align__(16) char pool[34816];   // As[128][40] union Qp[128][136]
    unsigned short (*As)[40] = (unsigned short(*)[40])pool;
    unsigned short (*Qp)[136] = (unsigned short(*)[136])pool;
    __shared__ unsigned short Pj[112][40];
    __shared__ unsigned short CsT[48][136];
    __shared__ float dg[128];
    int tid = threadIdx.x;
    int bh = blockIdx.x >> 6, b = bh >> 3, h = bh & 7;
    int n0 = (blockIdx.x & 63) * 128;
    for (int idx = tid; idx < 112 * 8; idx += 256) {
        int m = idx >> 3, f4 = idx & 7;
        if (m < NB) {
            float4 va = *(const float4*)(proj + m * 32 + f4 * 4);
            bf16x4 pk = {(short)f2b(va.x), (short)f2b(va.y), (short)f2b(va.z), (short)f2b(va.w)};
            *(bf16x4*)&Pj[m][f4 * 4] = pk;
        } else {
            *(bf16x4*)&Pj[m][f4 * 4] = (bf16x4){0, 0, 0, 0};
        }
    }
    // stage ctx^T (48 x 128)
    for (int idx = tid; idx < 128 * 12; idx += 256) {
        int m = idx / 12, c4 = idx - m * 12;
        float4 cv = *(const float4*)(ctx + ((size_t)bh * 128 + m) * 48 + c4 * 4);
        CsT[c4 * 4 + 0][m] = f2b(cv.x);
        CsT[c4 * 4 + 1][m] = f2b(cv.y);
        CsT[c4 * 4 + 2][m] = f2b(cv.z);
        CsT[c4 * 4 + 3][m] = f2b(cv.w);
    }
    int arow = tid >> 1, ahalf = tid & 1;
    {
        const float* qp_ = q + ((size_t)(b * NSEQ + n0 + arow) * 256 + h * 32 + ahalf * 16);
        float ssq = 0.f;
        #pragma unroll
        for (int fi = 0; fi < 4; ++fi) {
            float4 va = *(const float4*)(qp_ + fi * 4);
            ssq += va.x * va.x + va.y * va.y + va.z * va.z + va.w * va.w;
            bf16x4 pk = {(short)f2b(va.x), (short)f2b(va.y), (short)f2b(va.z), (short)f2b(va.w)};
            *(bf16x4*)&As[arow][ahalf * 16 + fi * 4] = pk;
        }
        ssq += __shfl_xor(ssq, 1);
        if (ahalf == 0) dg[arow] = ssq * c_diagf;
    }
    __syncthreads();
    int wave = tid >> 6, lane = tid & 63, lr = lane & 15, lg = lane >> 4;
    // xd MFMA -> regs
    f32x4 xds[2][7];
    #pragma unroll
    for (int mt = 0; mt < 2; ++mt) {
        bf16x8 af = *(bf16x8*)&As[(2 * wave + mt) * 16 + lr][lg * 8];
        #pragma unroll
        for (int nt = 0; nt < 7; ++nt) {
            bf16x8 bfp = *(bf16x8*)&Pj[nt * 16 + lr][lg * 8];
            f32x4 d = (f32x4){0.f, 0.f, 0.f, 0.f};
            xds[mt][nt] = __builtin_amdgcn_mfma_f32_16x16x32_bf16(af, bfp, d, 0, 0, 0);
        }
    }
    // per-row max (raw dot), mask pad cols
    float rmax[2][4];
    #pragma unroll
    for (int mt = 0; mt < 2; ++mt)
        #pragma unroll
        for (int r = 0; r < 4; ++r) {
            float mv = -1e30f;
            #pragma unroll
            for (int nt = 0; nt < 7; ++nt)
                if (!(nt == 6 && lr >= 14)) mv = fmaxf(mv, xds[mt][nt][r]);
            mv = fmaxf(mv, __shfl_xor(mv, 1));
            mv = fmaxf(mv, __shfl_xor(mv, 2));
            mv = fmaxf(mv, __shfl_xor(mv, 4));
            mv = fmaxf(mv, __shfl_xor(mv, 8));
            rmax[mt][r] = mv;
        }
    __syncthreads();   // As reads done; safe to write Qp over it
    #pragma unroll
    for (int mt = 0; mt < 2; ++mt)
        #pragma unroll
        for (int r = 0; r < 4; ++r) {
            int row = (2 * wave + mt) * 16 + lg * 4 + r;
            #pragma unroll
            for (int nt = 0; nt < 7; ++nt) {
                int m = nt * 16 + lr;
                float qpv = (m < NB)
                    ? c_ratio * (__expf((xds[mt][nt][r] - rmax[mt][r]) * c_dn - dg[row]) + 1e-4f)
                    : 0.f;
                Qp[row][m] = f2b(qpv);
            }
            Qp[row][112 + lr] = 0;   // zero pad cols 112..127
        }
    __syncthreads();
    // o MFMA: [128 rows] x [48 cols] over K=128
    f32x4 oacc[2][3];
    #pragma unroll
    for (int mt = 0; mt < 2; ++mt)
        #pragma unroll
        for (int nt = 0; nt < 3; ++nt) oacc[mt][nt] = (f32x4){0.f, 0.f, 0.f, 0.f};
    #pragma unroll
    for (int ks = 0; ks < 4; ++ks)
        #pragma unroll
        for (int mt = 0; mt < 2; ++mt) {
            bf16x8 af2 = *(bf16x8*)&Qp[(2 * wave + mt) * 16 + lr][ks * 32 + lg * 8];
            #pragma unroll
            for (int nt = 0; nt < 3; ++nt) {
                bf16x8 bf2 = *(bf16x8*)&CsT[nt * 16 + lr][ks * 32 + lg * 8];
                oacc[mt][nt] = __builtin_amdgcn_mfma_f32_16x16x32_bf16(af2, bf2, oacc[mt][nt], 0, 0, 0);
            }
        }
    #pragma unroll
    for (int mt = 0; mt < 2; ++mt)
        #pragma unroll
        for (int r = 0; r < 4; ++r) {
            int row = (2 * wave + mt) * 16 + lg * 4 + r;
            int n = n0 + row;
            float den = __shfl(oacc[mt][2][r], lane & 48);
            float inv = 1.0f / den;
            size_t base = (size_t)(b * NSEQ + n) * 256 + h * 32;
            o[base + lr] = oacc[mt][0][r] * inv;
            o[base + 16 + lr] = oacc[mt][1][r] * inv;
        }
}

extern "C" void kernel_launch(void* const* d_in, const int* in_sizes, int n_in,
                              void* d_out, int out_size, void* d_ws, size_t ws_size,
                              hipStream_t stream) {
    const float* x = (const float*)d_in[0];
    const float* proj = (const float*)d_in[1];
    const float* ln1_g = (const float*)d_in[2];
    const float* ln1_b = (const float*)d_in[3];
    const float* Wq = (const float*)d_in[4];
    const float* bq = (const float*)d_in[5];
    const float* Wk = (const float*)d_in[6];
    const float* bk = (const float*)d_in[7];
    const float* Wv = (const float*)d_in[8];
    const float* bv = (const float*)d_in[9];
    const float* Wo = (const float*)d_in[10];
    const float* bo = (const float*)d_in[11];
    const float* ln2_g = (const float*)d_in[12];
    const float* ln2_b = (const float*)d_in[13];
    const float* Wf1 = (const float*)d_in[14];
    const float* bf1 = (const float*)d_in[15];
    const float* Wf2 = (const float*)d_in[16];
    const float* bf2 = (const float*)d_in[17];

    float* h = (float*)d_out;
    float* ws = (float*)d_ws;
    const size_t ACT = (size_t)MROWS * DIM;          // 8,388,608 floats
    float* y = ws;
    float* q = ws + ACT;
    float* k = ws + 2 * ACT;
    float* v = ws + 3 * ACT;
    float* ctx = ws + 5 * ACT;                       // [32][128][48] f32
    unsigned* kmaxu = (unsigned*)(ctx + (size_t)BH * 128 * 48);
    unsigned short* wt = (unsigned short*)(kmaxu + 32);  // 655360 bf16 per layer x 4
    float* o = y;
    float* mid = q;                                  // [32768][1024] over q..spare

    const int WT_L = 655360;   // per-layer stride in wt (bf16 elems)
    const int CTXN = BH * 128 * 48 + BH;

    copy4_kernel<<<(int)(ACT / 4) / 256, 256, 0, stream>>>((const float4*)x, (float4*)h, (int)(ACT / 4));

    // pre-transpose+convert all weights (all 4 layers)
    wt_kernel<<<dim3(8, 8, 4), 256, 0, stream>>>(Wq, wt + 0, 256, 256, WT_L);
    wt_kernel<<<dim3(8, 8, 4), 256, 0, stream>>>(Wk, wt + 65536, 256, 256, WT_L);
    wt_kernel<<<dim3(8, 8, 4), 256, 0, stream>>>(Wv, wt + 131072, 256, 256, WT_L);
    wt_kernel<<<dim3(8, 8, 4), 256, 0, stream>>>(Wo, wt + 196608, 256, 256, WT_L);
    wt_kernel<<<dim3(8, 32, 4), 256, 0, stream>>>(Wf1, wt + 262144, 256, 1024, WT_L);
    wt_kernel<<<dim3(32, 8, 4), 256, 0, stream>>>(Wf2, wt + 524288, 1024, 256, WT_L);

    for (int i = 0; i < 4; ++i) {
        const float* proj_i = proj + (size_t)i * NB * DHEAD;
        const unsigned short* wl = wt + (size_t)i * WT_L;
        // --- attention ---
        ln_kernel<<<MROWS / 4, 256, 0, stream>>>(h, ln1_g + i * DIM, ln1_b + i * DIM, y);
        dim3 g256(2, 256);
        gemm_mfma<0><<<g256, 256, 0, stream>>>(y, wl + 0, bq + i * INNER, nullptr, q, INNER, DIM);
        gemm_mfma<0><<<g256, 256, 0, stream>>>(y, wl + 65536, bk + i * INNER, nullptr, k, INNER, DIM);
        gemm_mfma<0><<<g256, 256, 0, stream>>>(y, wl + 131072, bv + i * INNER, nullptr, v, INNER, DIM);

        zero_kernel<<<(CTXN + 255) / 256, 256, 0, stream>>>(ctx, CTXN);
        kmaxg_kernel<<<2048, 256, 0, stream>>>(k, proj_i, kmaxu);
        ctxg_kernel<<<dim3(8, BH), 256, 0, stream>>>(k, v, proj_i, kmaxu, ctx);
        og_kernel<<<BH * 64, 256, 0, stream>>>(q, proj_i, ctx, o);

        gemm_mfma<1><<<g256, 256, 0, stream>>>(o, wl + 196608, bo + i * DIM, h, h, DIM, INNER);

        // --- FFN ---
        ln_kernel<<<MROWS / 4, 256, 0, stream>>>(h, ln2_g + i * DIM, ln2_b + i * DIM, y);
        gemm_mfma<2><<<dim3(8, 256), 256, 0, stream>>>(y, wl + 262144, bf1 + i * FFDIM, nullptr, mid, FFDIM, DIM);
        gemm_mfma<1><<<dim3(2, 256), 256, 0, stream>>>(mid, wl + 524288, bf2 + i * DIM, h, h, DIM, FFDIM);
    }
}

// Round 6
// 1173.553 us; speedup vs baseline: 6.8249x; 1.9989x over previous
//
#include <hip/hip_runtime.h>
#include <math.h>

#define NSEQ 8192
#define BATCH 4
#define DIM 256
#define HEADS 8
#define DHEAD 32
#define NB 110
#define INNER 256
#define FFDIM 1024
#define MROWS (BATCH * NSEQ)   // 32768 rows
#define BH (BATCH * HEADS)     // 32

typedef __attribute__((ext_vector_type(8))) short bf16x8;
typedef __attribute__((ext_vector_type(4))) short bf16x4;
typedef __attribute__((ext_vector_type(4))) float f32x4;

constexpr float c_dn = 0.42044820762685725f;     // 32^-0.25
constexpr float c_diagf = 0.08838834764831845f;  // 0.5*dn*dn
constexpr float c_ratio = 0.09534625892455922f;  // 110^-0.5

__device__ __forceinline__ unsigned short f2b(float f) {
    unsigned u = __float_as_uint(f);
    unsigned r = (u + 0x7FFFu + ((u >> 16) & 1u)) >> 16;
    return (unsigned short)r;
}

// ---------------- util ----------------
__global__ __launch_bounds__(256) void copy4_kernel(const float4* __restrict__ src,
                                                    float4* __restrict__ dst, int n4) {
    int i = blockIdx.x * 256 + threadIdx.x;
    if (i < n4) dst[i] = src[i];
}
__global__ __launch_bounds__(256) void zero_kernel(float* __restrict__ p, int n) {
    int i = blockIdx.x * 256 + threadIdx.x;
    if (i < n) p[i] = 0.0f;
}

// ---------------- LayerNorm ----------------
__global__ __launch_bounds__(256) void ln_kernel(const float* __restrict__ x,
                                                 const float* __restrict__ g,
                                                 const float* __restrict__ bta,
                                                 float* __restrict__ y) {
    int wave = threadIdx.x >> 6, lane = threadIdx.x & 63;
    int row = blockIdx.x * 4 + wave;
    const float* xr = x + (size_t)row * DIM;
    float4 v = *(const float4*)(xr + lane * 4);
    float s = v.x + v.y + v.z + v.w;
    float sq = v.x * v.x + v.y * v.y + v.z * v.z + v.w * v.w;
    #pragma unroll
    for (int off = 32; off; off >>= 1) {
        s += __shfl_xor(s, off);
        sq += __shfl_xor(sq, off);
    }
    float mean = s * (1.0f / DIM);
    float var = sq * (1.0f / DIM) - mean * mean;
    float rstd = rsqrtf(var + 1e-5f);
    float4 gg = *(const float4*)(g + lane * 4);
    float4 bb = *(const float4*)(bta + lane * 4);
    float4 o;
    o.x = (v.x - mean) * rstd * gg.x + bb.x;
    o.y = (v.y - mean) * rstd * gg.y + bb.y;
    o.z = (v.z - mean) * rstd * gg.z + bb.z;
    o.w = (v.w - mean) * rstd * gg.w + bb.w;
    *(float4*)(y + (size_t)row * DIM + lane * 4) = o;
}

// ---------------- weight transpose+convert: out[l][n][k] = bf16(in[l][k][n]) ----------------
__global__ __launch_bounds__(256) void wt_kernel(const float* __restrict__ in,
                                                 unsigned short* __restrict__ out,
                                                 int K, int Nn, int lstride) {
    __shared__ float t32[32][33];
    int l = blockIdx.z;
    const float* inp = in + (size_t)l * K * Nn;
    unsigned short* outp = out + (size_t)l * lstride;
    int k0 = blockIdx.x * 32, n0 = blockIdx.y * 32;
    int tx = threadIdx.x & 31, ty = threadIdx.x >> 5;
    #pragma unroll
    for (int i = 0; i < 4; ++i)
        t32[ty + i * 8][tx] = inp[(size_t)(k0 + ty + i * 8) * Nn + n0 + tx];
    __syncthreads();
    #pragma unroll
    for (int i = 0; i < 4; ++i) {
        int r = ty + i * 8;  // n within tile
        outp[(size_t)(n0 + r) * K + k0 + tx] = f2b(t32[tx][r]);
    }
}

// ---------------- bf16 MFMA GEMM: C[M,N] = A[M,K](f32) @ Wt[N,K]^T(bf16) + epilogue ----------------
// EPI 0: +bias   EPI 1: +bias+res   EPI 2: gelu(+bias)
template <int EPI>
__global__ __launch_bounds__(256) void gemm_mfma(const float* __restrict__ A,
                                                 const unsigned short* __restrict__ Wt,
                                                 const float* __restrict__ bias,
                                                 const float* __restrict__ res,
                                                 float* __restrict__ C,
                                                 int Nn, int K) {
    __shared__ unsigned short As[128][40];
    __shared__ unsigned short Bs[128][40];
    int tid = threadIdx.x;
    int m0 = blockIdx.y * 128, n0 = blockIdx.x * 128;
    int wave = tid >> 6, lane = tid & 63;
    int wm = (wave >> 1) * 64, wn = (wave & 1) * 64;
    int lr = lane & 15, lg = lane >> 4;
    f32x4 acc[4][4];
    #pragma unroll
    for (int i = 0; i < 4; ++i)
        #pragma unroll
        for (int j = 0; j < 4; ++j) acc[i][j] = (f32x4){0.f, 0.f, 0.f, 0.f};
    int arow = tid >> 1, ahalf = tid & 1;
    for (int kt = 0; kt < K; kt += 32) {
        const float* ap = A + (size_t)(m0 + arow) * K + kt + ahalf * 16;
        #pragma unroll
        for (int fi = 0; fi < 4; ++fi) {
            float4 va = *(const float4*)(ap + fi * 4);
            bf16x4 pk = {(short)f2b(va.x), (short)f2b(va.y), (short)f2b(va.z), (short)f2b(va.w)};
            *(bf16x4*)&As[arow][ahalf * 16 + fi * 4] = pk;
        }
        const unsigned short* bp = Wt + (size_t)(n0 + arow) * K + kt + ahalf * 16;
        *(bf16x8*)&Bs[arow][ahalf * 16] = *(const bf16x8*)bp;
        *(bf16x8*)&Bs[arow][ahalf * 16 + 8] = *(const bf16x8*)(bp + 8);
        __syncthreads();
        bf16x8 af[4], bfv[4];
        #pragma unroll
        for (int i = 0; i < 4; ++i) af[i] = *(bf16x8*)&As[wm + i * 16 + lr][lg * 8];
        #pragma unroll
        for (int j = 0; j < 4; ++j) bfv[j] = *(bf16x8*)&Bs[wn + j * 16 + lr][lg * 8];
        #pragma unroll
        for (int i = 0; i < 4; ++i)
            #pragma unroll
            for (int j = 0; j < 4; ++j)
                acc[i][j] = __builtin_amdgcn_mfma_f32_16x16x32_bf16(af[i], bfv[j], acc[i][j], 0, 0, 0);
        __syncthreads();
    }
    #pragma unroll
    for (int i = 0; i < 4; ++i) {
        #pragma unroll
        for (int j = 0; j < 4; ++j) {
            int col = n0 + wn + j * 16 + lr;
            float bv = bias[col];
            #pragma unroll
            for (int r = 0; r < 4; ++r) {
                int row = m0 + wm + i * 16 + lg * 4 + r;
                float c = acc[i][j][r] + bv;
                if (EPI == 1) c += res[(size_t)row * Nn + col];
                if (EPI == 2) {
                    float u = c;
                    c = 0.5f * u * (1.0f + tanhf(0.7978845608028654f * (u + 0.044715f * u * u * u)));
                }
                C[(size_t)row * Nn + col] = c;
            }
        }
    }
}

// ---------------- kmaxg: per-block partial max over n,m of dn*(k . proj_m); NO atomics ----------------
__global__ __launch_bounds__(256) void kmaxg_kernel(const float* __restrict__ k,
                                                    const float* __restrict__ proj,
                                                    float* __restrict__ partial) {
    __shared__ unsigned short As[128][40];
    __shared__ unsigned short Pj[112][40];
    __shared__ float wmax[4][8];
    int tid = threadIdx.x;
    int r0 = blockIdx.x * 128;     // flat row in [262144] = (b*8192+n)*8+h
    for (int idx = tid; idx < 112 * 8; idx += 256) {
        int m = idx >> 3, f4 = idx & 7;
        if (m < NB) {
            float4 va = *(const float4*)(proj + m * 32 + f4 * 4);
            bf16x4 pk = {(short)f2b(va.x), (short)f2b(va.y), (short)f2b(va.z), (short)f2b(va.w)};
            *(bf16x4*)&Pj[m][f4 * 4] = pk;
        } else {
            *(bf16x4*)&Pj[m][f4 * 4] = (bf16x4){0, 0, 0, 0};
        }
    }
    int arow = tid >> 1, ahalf = tid & 1;
    const float* ap = k + (size_t)(r0 + arow) * 32 + ahalf * 16;
    #pragma unroll
    for (int fi = 0; fi < 4; ++fi) {
        float4 va = *(const float4*)(ap + fi * 4);
        bf16x4 pk = {(short)f2b(va.x), (short)f2b(va.y), (short)f2b(va.z), (short)f2b(va.w)};
        *(bf16x4*)&As[arow][ahalf * 16 + fi * 4] = pk;
    }
    __syncthreads();
    int wave = tid >> 6, lane = tid & 63, lr = lane & 15, lg = lane >> 4;
    float mymax[4] = {-1e30f, -1e30f, -1e30f, -1e30f};
    #pragma unroll
    for (int mt = 0; mt < 2; ++mt) {
        bf16x8 af = *(bf16x8*)&As[(2 * wave + mt) * 16 + lr][lg * 8];
        #pragma unroll
        for (int nt = 0; nt < 7; ++nt) {
            bf16x8 bfp = *(bf16x8*)&Pj[nt * 16 + lr][lg * 8];
            f32x4 d = (f32x4){0.f, 0.f, 0.f, 0.f};
            d = __builtin_amdgcn_mfma_f32_16x16x32_bf16(af, bfp, d, 0, 0, 0);
            if (!(nt == 6 && lr >= 14)) {
                #pragma unroll
                for (int r = 0; r < 4; ++r) mymax[r] = fmaxf(mymax[r], d[r]);
            }
        }
    }
    // reduce over feature dim (lane bits 0..3) and row-pairs with same h (lane bit 5)
    #pragma unroll
    for (int r = 0; r < 4; ++r) {
        float v = mymax[r];
        v = fmaxf(v, __shfl_xor(v, 1));
        v = fmaxf(v, __shfl_xor(v, 2));
        v = fmaxf(v, __shfl_xor(v, 4));
        v = fmaxf(v, __shfl_xor(v, 8));
        v = fmaxf(v, __shfl_xor(v, 32));
        mymax[r] = v;
    }
    if (lane == 0 || lane == 16) {
        int hb = (lane >> 4) & 1;
        #pragma unroll
        for (int r = 0; r < 4; ++r) wmax[wave][4 * hb + r] = mymax[r];
    }
    __syncthreads();
    if (tid < 8) {
        float m = fmaxf(fmaxf(wmax[0][tid], wmax[1][tid]), fmaxf(wmax[2][tid], wmax[3][tid]));
        partial[blockIdx.x * 8 + tid] = m * c_dn;
    }
}

// ---------------- kreduce: kmaxf[bh] = max over 512 partials ----------------
__global__ __launch_bounds__(256) void kreduce_kernel(const float* __restrict__ partial,
                                                      float* __restrict__ kmaxf) {
    __shared__ float wred[4];
    int bh = blockIdx.x, b = bh >> 3, h = bh & 7;
    int tid = threadIdx.x;
    float m = fmaxf(partial[(b * 512 + tid) * 8 + h], partial[(b * 512 + 256 + tid) * 8 + h]);
    #pragma unroll
    for (int off = 32; off; off >>= 1) m = fmaxf(m, __shfl_xor(m, off));
    if ((tid & 63) == 0) wred[tid >> 6] = m;
    __syncthreads();
    if (tid == 0)
        kmaxf[bh] = fmaxf(fmaxf(wred[0], wred[1]), fmaxf(wred[2], wred[3]));
}

// ---------------- ctxg: fused kp + ctx accumulation (one bh per blockIdx.y) ----------------
__global__ __launch_bounds__(256) void ctxg_kernel(const float* __restrict__ k,
                                                   const float* __restrict__ v,
                                                   const float* __restrict__ proj,
                                                   const float* __restrict__ kmaxf,
                                                   float* __restrict__ ctx) {
    __shared__ __align__(16) char pool[34816];   // As[128][40] (10240B) union KpT[128][136] (34816B)
    unsigned short (*As)[40] = (unsigned short(*)[40])pool;
    unsigned short (*KpT)[136] = (unsigned short(*)[136])pool;
    __shared__ unsigned short Pj[112][40];
    __shared__ unsigned short VsT[48][136];
    __shared__ float dg[128];
    int tid = threadIdx.x;
    int bh = blockIdx.y, b = bh >> 3, h = bh & 7;
    int n_base = blockIdx.x * 512;
    float mx = kmaxf[bh];
    // pjT
    for (int idx = tid; idx < 112 * 8; idx += 256) {
        int m = idx >> 3, f4 = idx & 7;
        if (m < NB) {
            float4 va = *(const float4*)(proj + m * 32 + f4 * 4);
            bf16x4 pk = {(short)f2b(va.x), (short)f2b(va.y), (short)f2b(va.z), (short)f2b(va.w)};
            *(bf16x4*)&Pj[m][f4 * 4] = pk;
        } else {
            *(bf16x4*)&Pj[m][f4 * 4] = (bf16x4){0, 0, 0, 0};
        }
    }
    // KpT pad rows 112..127 zero (outside As byte range; persists)
    for (int idx = tid; idx < 16 * 136; idx += 256) KpT[112 + idx / 136][idx % 136] = 0;
    // VsT rows 32..47: ones row + zero pad (persist across sub-iters)
    for (int idx = tid; idx < 16 * 128; idx += 256) {
        int rr = 32 + (idx >> 7), nn = idx & 127;
        VsT[rr][nn] = (rr == 32) ? (unsigned short)0x3F80 : (unsigned short)0;
    }
    int wave = tid >> 6, lane = tid & 63, lr = lane & 15, lg = lane >> 4;
    int arow = tid >> 1, ahalf = tid & 1;
    f32x4 ctxacc[2][3];
    #pragma unroll
    for (int mt = 0; mt < 2; ++mt)
        #pragma unroll
        for (int nt = 0; nt < 3; ++nt) ctxacc[mt][nt] = (f32x4){0.f, 0.f, 0.f, 0.f};

    for (int ni = 0; ni < 4; ++ni) {
        int n0 = n_base + ni * 128;
        // stage k slice (f32->bf16) + diag
        {
            const float* kp_ = k + ((size_t)(b * NSEQ + n0 + arow) * 256 + h * 32 + ahalf * 16);
            float ssq = 0.f;
            #pragma unroll
            for (int fi = 0; fi < 4; ++fi) {
                float4 va = *(const float4*)(kp_ + fi * 4);
                ssq += va.x * va.x + va.y * va.y + va.z * va.z + va.w * va.w;
                bf16x4 pk = {(short)f2b(va.x), (short)f2b(va.y), (short)f2b(va.z), (short)f2b(va.w)};
                *(bf16x4*)&As[arow][ahalf * 16 + fi * 4] = pk;
            }
            ssq += __shfl_xor(ssq, 1);
            if (ahalf == 0) dg[arow] = ssq * c_diagf;
        }
        // stage v transposed
        #pragma unroll
        for (int it = 0; it < 4; ++it) {
            int idx = it * 256 + tid;
            int nn = idx >> 3, f4 = idx & 7;
            float4 vv = *(const float4*)(v + ((size_t)(b * NSEQ + n0 + nn) * 256 + h * 32 + f4 * 4));
            VsT[f4 * 4 + 0][nn] = f2b(vv.x);
            VsT[f4 * 4 + 1][nn] = f2b(vv.y);
            VsT[f4 * 4 + 2][nn] = f2b(vv.z);
            VsT[f4 * 4 + 3][nn] = f2b(vv.w);
        }
        __syncthreads();
        // xd MFMA -> regs
        f32x4 xds[2][7];
        #pragma unroll
        for (int mt = 0; mt < 2; ++mt) {
            bf16x8 af = *(bf16x8*)&As[(2 * wave + mt) * 16 + lr][lg * 8];
            #pragma unroll
            for (int nt = 0; nt < 7; ++nt) {
                bf16x8 bfp = *(bf16x8*)&Pj[nt * 16 + lr][lg * 8];
                f32x4 d = (f32x4){0.f, 0.f, 0.f, 0.f};
                xds[mt][nt] = __builtin_amdgcn_mfma_f32_16x16x32_bf16(af, bfp, d, 0, 0, 0);
            }
        }
        __syncthreads();   // As reads done; safe to overwrite via KpT
        // exp -> KpT (bf16), transposed write
        #pragma unroll
        for (int mt = 0; mt < 2; ++mt)
            #pragma unroll
            for (int nt = 0; nt < 7; ++nt) {
                int m = nt * 16 + lr;
                #pragma unroll
                for (int r = 0; r < 4; ++r) {
                    int nn = (2 * wave + mt) * 16 + lg * 4 + r;
                    float kpv = (m < NB) ? c_ratio * (__expf(xds[mt][nt][r] * c_dn - dg[nn] - mx) + 1e-4f) : 0.f;
                    KpT[m][nn] = f2b(kpv);
                }
            }
        __syncthreads();
        // ctx MFMA accumulate: ctx[m][c] += sum_n kp[n][m]*vext[n][c]
        #pragma unroll
        for (int ks = 0; ks < 4; ++ks)
            #pragma unroll
            for (int mt = 0; mt < 2; ++mt) {
                bf16x8 af2 = *(bf16x8*)&KpT[(2 * wave + mt) * 16 + lr][ks * 32 + lg * 8];
                #pragma unroll
                for (int nt = 0; nt < 3; ++nt) {
                    bf16x8 bf2 = *(bf16x8*)&VsT[nt * 16 + lr][ks * 32 + lg * 8];
                    ctxacc[mt][nt] = __builtin_amdgcn_mfma_f32_16x16x32_bf16(af2, bf2, ctxacc[mt][nt], 0, 0, 0);
                }
            }
        __syncthreads();
    }
    #pragma unroll
    for (int mt = 0; mt < 2; ++mt)
        #pragma unroll
        for (int nt = 0; nt < 3; ++nt)
            #pragma unroll
            for (int r = 0; r < 4; ++r) {
                int m = (2 * wave + mt) * 16 + lg * 4 + r;
                atomicAdd(&ctx[((size_t)bh * 128 + m) * 48 + nt * 16 + lr], ctxacc[mt][nt][r]);
            }
}

// ---------------- og: fused qp + output (one bh per 64 blocks) ----------------
__global__ __launch_bounds__(256) void og_kernel(const float* __restrict__ q,
                                                 const float* __restrict__ proj,
                                                 const float* __restrict__ ctx,
                                                 float* __restrict__ o) {
    __shared__ __align__(16) char pool[34816];   // As[128][40] union Qp[128][136]
    unsigned short (*As)[40] = (unsigned short(*)[40])pool;
    unsigned short (*Qp)[136] = (unsigned short(*)[136])pool;
    __shared__ unsigned short Pj[112][40];
    __shared__ unsigned short CsT[48][136];
    __shared__ float dg[128];
    int tid = threadIdx.x;
    int bh = blockIdx.x >> 6, b = bh >> 3, h = bh & 7;
    int n0 = (blockIdx.x & 63) * 128;
    for (int idx = tid; idx < 112 * 8; idx += 256) {
        int m = idx >> 3, f4 = idx & 7;
        if (m < NB) {
            float4 va = *(const float4*)(proj + m * 32 + f4 * 4);
            bf16x4 pk = {(short)f2b(va.x), (short)f2b(va.y), (short)f2b(va.z), (short)f2b(va.w)};
            *(bf16x4*)&Pj[m][f4 * 4] = pk;
        } else {
            *(bf16x4*)&Pj[m][f4 * 4] = (bf16x4){0, 0, 0, 0};
        }
    }
    // stage ctx^T (48 x 128)
    for (int idx = tid; idx < 128 * 12; idx += 256) {
        int m = idx / 12, c4 = idx - m * 12;
        float4 cv = *(const float4*)(ctx + ((size_t)bh * 128 + m) * 48 + c4 * 4);
        CsT[c4 * 4 + 0][m] = f2b(cv.x);
        CsT[c4 * 4 + 1][m] = f2b(cv.y);
        CsT[c4 * 4 + 2][m] = f2b(cv.z);
        CsT[c4 * 4 + 3][m] = f2b(cv.w);
    }
    int arow = tid >> 1, ahalf = tid & 1;
    {
        const float* qp_ = q + ((size_t)(b * NSEQ + n0 + arow) * 256 + h * 32 + ahalf * 16);
        float ssq = 0.f;
        #pragma unroll
        for (int fi = 0; fi < 4; ++fi) {
            float4 va = *(const float4*)(qp_ + fi * 4);
            ssq += va.x * va.x + va.y * va.y + va.z * va.z + va.w * va.w;
            bf16x4 pk = {(short)f2b(va.x), (short)f2b(va.y), (short)f2b(va.z), (short)f2b(va.w)};
            *(bf16x4*)&As[arow][ahalf * 16 + fi * 4] = pk;
        }
        ssq += __shfl_xor(ssq, 1);
        if (ahalf == 0) dg[arow] = ssq * c_diagf;
    }
    __syncthreads();
    int wave = tid >> 6, lane = tid & 63, lr = lane & 15, lg = lane >> 4;
    // xd MFMA -> regs
    f32x4 xds[2][7];
    #pragma unroll
    for (int mt = 0; mt < 2; ++mt) {
        bf16x8 af = *(bf16x8*)&As[(2 * wave + mt) * 16 + lr][lg * 8];
        #pragma unroll
        for (int nt = 0; nt < 7; ++nt) {
            bf16x8 bfp = *(bf16x8*)&Pj[nt * 16 + lr][lg * 8];
            f32x4 d = (f32x4){0.f, 0.f, 0.f, 0.f};
            xds[mt][nt] = __builtin_amdgcn_mfma_f32_16x16x32_bf16(af, bfp, d, 0, 0, 0);
        }
    }
    // per-row max (raw dot), mask pad cols
    float rmax[2][4];
    #pragma unroll
    for (int mt = 0; mt < 2; ++mt)
        #pragma unroll
        for (int r = 0; r < 4; ++r) {
            float mv = -1e30f;
            #pragma unroll
            for (int nt = 0; nt < 7; ++nt)
                if (!(nt == 6 && lr >= 14)) mv = fmaxf(mv, xds[mt][nt][r]);
            mv = fmaxf(mv, __shfl_xor(mv, 1));
            mv = fmaxf(mv, __shfl_xor(mv, 2));
            mv = fmaxf(mv, __shfl_xor(mv, 4));
            mv = fmaxf(mv, __shfl_xor(mv, 8));
            rmax[mt][r] = mv;
        }
    __syncthreads();   // As reads done; safe to write Qp over it
    #pragma unroll
    for (int mt = 0; mt < 2; ++mt)
        #pragma unroll
        for (int r = 0; r < 4; ++r) {
            int row = (2 * wave + mt) * 16 + lg * 4 + r;
            #pragma unroll
            for (int nt = 0; nt < 7; ++nt) {
                int m = nt * 16 + lr;
                float qpv = (m < NB)
                    ? c_ratio * (__expf((xds[mt][nt][r] - rmax[mt][r]) * c_dn - dg[row]) + 1e-4f)
                    : 0.f;
                Qp[row][m] = f2b(qpv);
            }
            Qp[row][112 + lr] = 0;   // zero pad cols 112..127
        }
    __syncthreads();
    // o MFMA: [128 rows] x [48 cols] over K=128
    f32x4 oacc[2][3];
    #pragma unroll
    for (int mt = 0; mt < 2; ++mt)
        #pragma unroll
        for (int nt = 0; nt < 3; ++nt) oacc[mt][nt] = (f32x4){0.f, 0.f, 0.f, 0.f};
    #pragma unroll
    for (int ks = 0; ks < 4; ++ks)
        #pragma unroll
        for (int mt = 0; mt < 2; ++mt) {
            bf16x8 af2 = *(bf16x8*)&Qp[(2 * wave + mt) * 16 + lr][ks * 32 + lg * 8];
            #pragma unroll
            for (int nt = 0; nt < 3; ++nt) {
                bf16x8 bf2 = *(bf16x8*)&CsT[nt * 16 + lr][ks * 32 + lg * 8];
                oacc[mt][nt] = __builtin_amdgcn_mfma_f32_16x16x32_bf16(af2, bf2, oacc[mt][nt], 0, 0, 0);
            }
        }
    #pragma unroll
    for (int mt = 0; mt < 2; ++mt)
        #pragma unroll
        for (int r = 0; r < 4; ++r) {
            int row = (2 * wave + mt) * 16 + lg * 4 + r;
            int n = n0 + row;
            float den = __shfl(oacc[mt][2][r], lane & 48);
            float inv = 1.0f / den;
            size_t base = (size_t)(b * NSEQ + n) * 256 + h * 32;
            o[base + lr] = oacc[mt][0][r] * inv;
            o[base + 16 + lr] = oacc[mt][1][r] * inv;
        }
}

extern "C" void kernel_launch(void* const* d_in, const int* in_sizes, int n_in,
                              void* d_out, int out_size, void* d_ws, size_t ws_size,
                              hipStream_t stream) {
    const float* x = (const float*)d_in[0];
    const float* proj = (const float*)d_in[1];
    const float* ln1_g = (const float*)d_in[2];
    const float* ln1_b = (const float*)d_in[3];
    const float* Wq = (const float*)d_in[4];
    const float* bq = (const float*)d_in[5];
    const float* Wk = (const float*)d_in[6];
    const float* bk = (const float*)d_in[7];
    const float* Wv = (const float*)d_in[8];
    const float* bv = (const float*)d_in[9];
    const float* Wo = (const float*)d_in[10];
    const float* bo = (const float*)d_in[11];
    const float* ln2_g = (const float*)d_in[12];
    const float* ln2_b = (const float*)d_in[13];
    const float* Wf1 = (const float*)d_in[14];
    const float* bf1 = (const float*)d_in[15];
    const float* Wf2 = (const float*)d_in[16];
    const float* bf2 = (const float*)d_in[17];

    float* h = (float*)d_out;
    float* ws = (float*)d_ws;
    const size_t ACT = (size_t)MROWS * DIM;          // 8,388,608 floats
    float* y = ws;
    float* q = ws + ACT;
    float* k = ws + 2 * ACT;
    float* v = ws + 3 * ACT;
    float* ctx = ws + 5 * ACT;                       // [32][128][48] f32
    float* kmaxf = ctx + (size_t)BH * 128 * 48;
    unsigned short* wt = (unsigned short*)(kmaxf + 32);
    float* o = y;
    float* mid = q;                                  // [32768][1024] over q..spare
    // partial maxes live in y (dead between QKV GEMMs and og); 2048*8 floats << ACT
    float* partial = y;

    // per-layer wt stride: 4*(256*256) + 2*(256*1024) = 786432 bf16  (was 655360: layer overlap bug)
    const int WT_L = 786432;
    const int CTXN = BH * 128 * 48;

    copy4_kernel<<<(int)(ACT / 4) / 256, 256, 0, stream>>>((const float4*)x, (float4*)h, (int)(ACT / 4));

    // pre-transpose+convert all weights (all 4 layers)
    wt_kernel<<<dim3(8, 8, 4), 256, 0, stream>>>(Wq, wt + 0, 256, 256, WT_L);
    wt_kernel<<<dim3(8, 8, 4), 256, 0, stream>>>(Wk, wt + 65536, 256, 256, WT_L);
    wt_kernel<<<dim3(8, 8, 4), 256, 0, stream>>>(Wv, wt + 131072, 256, 256, WT_L);
    wt_kernel<<<dim3(8, 8, 4), 256, 0, stream>>>(Wo, wt + 196608, 256, 256, WT_L);
    wt_kernel<<<dim3(8, 32, 4), 256, 0, stream>>>(Wf1, wt + 262144, 256, 1024, WT_L);
    wt_kernel<<<dim3(32, 8, 4), 256, 0, stream>>>(Wf2, wt + 524288, 1024, 256, WT_L);

    for (int i = 0; i < 4; ++i) {
        const float* proj_i = proj + (size_t)i * NB * DHEAD;
        const unsigned short* wl = wt + (size_t)i * WT_L;
        // --- attention ---
        ln_kernel<<<MROWS / 4, 256, 0, stream>>>(h, ln1_g + i * DIM, ln1_b + i * DIM, y);
        dim3 g256(2, 256);
        gemm_mfma<0><<<g256, 256, 0, stream>>>(y, wl + 0, bq + i * INNER, nullptr, q, INNER, DIM);
        gemm_mfma<0><<<g256, 256, 0, stream>>>(y, wl + 65536, bk + i * INNER, nullptr, k, INNER, DIM);
        gemm_mfma<0><<<g256, 256, 0, stream>>>(y, wl + 131072, bv + i * INNER, nullptr, v, INNER, DIM);

        zero_kernel<<<(CTXN + 255) / 256, 256, 0, stream>>>(ctx, CTXN);
        kmaxg_kernel<<<2048, 256, 0, stream>>>(k, proj_i, partial);
        kreduce_kernel<<<BH, 256, 0, stream>>>(partial, kmaxf);
        ctxg_kernel<<<dim3(16, BH), 256, 0, stream>>>(k, v, proj_i, kmaxf, ctx);
        og_kernel<<<BH * 64, 256, 0, stream>>>(q, proj_i, ctx, o);

        gemm_mfma<1><<<g256, 256, 0, stream>>>(o, wl + 196608, bo + i * DIM, h, h, DIM, INNER);

        // --- FFN ---
        ln_kernel<<<MROWS / 4, 256, 0, stream>>>(h, ln2_g + i * DIM, ln2_b + i * DIM, y);
        gemm_mfma<2><<<dim3(8, 256), 256, 0, stream>>>(y, wl + 262144, bf1 + i * FFDIM, nullptr, mid, FFDIM, DIM);
        gemm_mfma<1><<<dim3(2, 256), 256, 0, stream>>>(mid, wl + 524288, bf2 + i * DIM, h, h, DIM, FFDIM);
    }
}

// Round 7
// 962.118 us; speedup vs baseline: 8.3247x; 1.2198x over previous
//
#include <hip/hip_runtime.h>
#include <math.h>

#define NSEQ 8192
#define BATCH 4
#define DIM 256
#define HEADS 8
#define DHEAD 32
#define NB 110
#define INNER 256
#define FFDIM 1024
#define MROWS (BATCH * NSEQ)   // 32768 rows
#define BH (BATCH * HEADS)     // 32

typedef __attribute__((ext_vector_type(8))) short bf16x8;
typedef __attribute__((ext_vector_type(4))) short bf16x4;
typedef __attribute__((ext_vector_type(4))) float f32x4;

constexpr float c_dn = 0.42044820762685725f;     // 32^-0.25
constexpr float c_diagf = 0.08838834764831845f;  // 0.5*dn*dn
constexpr float c_ratio = 0.09534625892455922f;  // 110^-0.5

__device__ __forceinline__ unsigned short f2b(float f) {
    unsigned u = __float_as_uint(f);
    unsigned r = (u + 0x7FFFu + ((u >> 16) & 1u)) >> 16;
    return (unsigned short)r;
}
__device__ __forceinline__ float b2f(unsigned short u) {
    return __uint_as_float((unsigned)u << 16);
}

// ---------------- util ----------------
__global__ __launch_bounds__(256) void copy4_kernel(const float4* __restrict__ src,
                                                    float4* __restrict__ dst, int n4) {
    int i = blockIdx.x * 256 + threadIdx.x;
    if (i < n4) dst[i] = src[i];
}
__global__ __launch_bounds__(256) void zero_kernel(float* __restrict__ p, int n) {
    int i = blockIdx.x * 256 + threadIdx.x;
    if (i < n) p[i] = 0.0f;
}

// ---------------- LayerNorm: f32 in -> bf16 out ----------------
__global__ __launch_bounds__(256) void ln_kernel(const float* __restrict__ x,
                                                 const float* __restrict__ g,
                                                 const float* __restrict__ bta,
                                                 unsigned short* __restrict__ y) {
    int wave = threadIdx.x >> 6, lane = threadIdx.x & 63;
    int row = blockIdx.x * 4 + wave;
    const float* xr = x + (size_t)row * DIM;
    float4 v = *(const float4*)(xr + lane * 4);
    float s = v.x + v.y + v.z + v.w;
    float sq = v.x * v.x + v.y * v.y + v.z * v.z + v.w * v.w;
    #pragma unroll
    for (int off = 32; off; off >>= 1) {
        s += __shfl_xor(s, off);
        sq += __shfl_xor(sq, off);
    }
    float mean = s * (1.0f / DIM);
    float var = sq * (1.0f / DIM) - mean * mean;
    float rstd = rsqrtf(var + 1e-5f);
    float4 gg = *(const float4*)(g + lane * 4);
    float4 bb = *(const float4*)(bta + lane * 4);
    bf16x4 o;
    o[0] = (short)f2b((v.x - mean) * rstd * gg.x + bb.x);
    o[1] = (short)f2b((v.y - mean) * rstd * gg.y + bb.y);
    o[2] = (short)f2b((v.z - mean) * rstd * gg.z + bb.z);
    o[3] = (short)f2b((v.w - mean) * rstd * gg.w + bb.w);
    *(bf16x4*)(y + (size_t)row * DIM + lane * 4) = o;
}

// ---------------- weight transpose+convert: out[l][n][k] = bf16(in[l][k][n]) ----------------
__global__ __launch_bounds__(256) void wt_kernel(const float* __restrict__ in,
                                                 unsigned short* __restrict__ out,
                                                 int K, int Nn, int lstride) {
    __shared__ float t32[32][33];
    int l = blockIdx.z;
    const float* inp = in + (size_t)l * K * Nn;
    unsigned short* outp = out + (size_t)l * lstride;
    int k0 = blockIdx.x * 32, n0 = blockIdx.y * 32;
    int tx = threadIdx.x & 31, ty = threadIdx.x >> 5;
    #pragma unroll
    for (int i = 0; i < 4; ++i)
        t32[ty + i * 8][tx] = inp[(size_t)(k0 + ty + i * 8) * Nn + n0 + tx];
    __syncthreads();
    #pragma unroll
    for (int i = 0; i < 4; ++i) {
        int r = ty + i * 8;  // n within tile
        outp[(size_t)(n0 + r) * K + k0 + tx] = f2b(t32[tx][r]);
    }
}

// ---------------- bf16 MFMA GEMM: C[M,N] = A[M,K](bf16) @ Wt[N,K]^T(bf16) + epilogue ----------------
// EPI 0: +bias -> bf16 out   EPI 1: +bias+res(f32) -> f32 out   EPI 2: gelu(+bias) -> bf16 out
template <int EPI>
__global__ __launch_bounds__(256) void gemm_mfma(const unsigned short* __restrict__ A,
                                                 const unsigned short* __restrict__ Wt,
                                                 const float* __restrict__ bias,
                                                 const float* __restrict__ res,
                                                 void* __restrict__ Cv,
                                                 int Nn, int K) {
    __shared__ unsigned short As[128][40];
    __shared__ unsigned short Bs[128][40];
    int tid = threadIdx.x;
    int m0 = blockIdx.y * 128, n0 = blockIdx.x * 128;
    int wave = tid >> 6, lane = tid & 63;
    int wm = (wave >> 1) * 64, wn = (wave & 1) * 64;
    int lr = lane & 15, lg = lane >> 4;
    f32x4 acc[4][4];
    #pragma unroll
    for (int i = 0; i < 4; ++i)
        #pragma unroll
        for (int j = 0; j < 4; ++j) acc[i][j] = (f32x4){0.f, 0.f, 0.f, 0.f};
    int arow = tid >> 1, ahalf = tid & 1;
    for (int kt = 0; kt < K; kt += 32) {
        const unsigned short* ap = A + (size_t)(m0 + arow) * K + kt + ahalf * 16;
        *(bf16x8*)&As[arow][ahalf * 16] = *(const bf16x8*)ap;
        *(bf16x8*)&As[arow][ahalf * 16 + 8] = *(const bf16x8*)(ap + 8);
        const unsigned short* bp = Wt + (size_t)(n0 + arow) * K + kt + ahalf * 16;
        *(bf16x8*)&Bs[arow][ahalf * 16] = *(const bf16x8*)bp;
        *(bf16x8*)&Bs[arow][ahalf * 16 + 8] = *(const bf16x8*)(bp + 8);
        __syncthreads();
        bf16x8 af[4], bfv[4];
        #pragma unroll
        for (int i = 0; i < 4; ++i) af[i] = *(bf16x8*)&As[wm + i * 16 + lr][lg * 8];
        #pragma unroll
        for (int j = 0; j < 4; ++j) bfv[j] = *(bf16x8*)&Bs[wn + j * 16 + lr][lg * 8];
        #pragma unroll
        for (int i = 0; i < 4; ++i)
            #pragma unroll
            for (int j = 0; j < 4; ++j)
                acc[i][j] = __builtin_amdgcn_mfma_f32_16x16x32_bf16(af[i], bfv[j], acc[i][j], 0, 0, 0);
        __syncthreads();
    }
    #pragma unroll
    for (int i = 0; i < 4; ++i) {
        #pragma unroll
        for (int j = 0; j < 4; ++j) {
            int col = n0 + wn + j * 16 + lr;
            float bv = bias[col];
            #pragma unroll
            for (int r = 0; r < 4; ++r) {
                int row = m0 + wm + i * 16 + lg * 4 + r;
                float c = acc[i][j][r] + bv;
                if (EPI == 1) {
                    c += res[(size_t)row * Nn + col];
                    ((float*)Cv)[(size_t)row * Nn + col] = c;
                } else if (EPI == 2) {
                    float u = c;
                    float t = 1.5957691216057308f * (u + 0.044715f * u * u * u);  // 2*0.79788456*(...)
                    float gv = u / (1.0f + __expf(-t));
                    ((unsigned short*)Cv)[(size_t)row * Nn + col] = f2b(gv);
                } else {
                    ((unsigned short*)Cv)[(size_t)row * Nn + col] = f2b(c);
                }
            }
        }
    }
}

// ---------------- kmaxg: per-block partial max over n,m of dn*(k . proj_m); NO atomics ----------------
__global__ __launch_bounds__(256) void kmaxg_kernel(const unsigned short* __restrict__ k,
                                                    const float* __restrict__ proj,
                                                    float* __restrict__ partial) {
    __shared__ unsigned short As[128][40];
    __shared__ unsigned short Pj[112][40];
    __shared__ float wmax[4][8];
    int tid = threadIdx.x;
    int r0 = blockIdx.x * 128;     // flat row in [262144] = (b*8192+n)*8+h
    for (int idx = tid; idx < 112 * 8; idx += 256) {
        int m = idx >> 3, f4 = idx & 7;
        if (m < NB) {
            float4 va = *(const float4*)(proj + m * 32 + f4 * 4);
            bf16x4 pk = {(short)f2b(va.x), (short)f2b(va.y), (short)f2b(va.z), (short)f2b(va.w)};
            *(bf16x4*)&Pj[m][f4 * 4] = pk;
        } else {
            *(bf16x4*)&Pj[m][f4 * 4] = (bf16x4){0, 0, 0, 0};
        }
    }
    int arow = tid >> 1, ahalf = tid & 1;
    const unsigned short* ap = k + (size_t)(r0 + arow) * 32 + ahalf * 16;
    *(bf16x8*)&As[arow][ahalf * 16] = *(const bf16x8*)ap;
    *(bf16x8*)&As[arow][ahalf * 16 + 8] = *(const bf16x8*)(ap + 8);
    __syncthreads();
    int wave = tid >> 6, lane = tid & 63, lr = lane & 15, lg = lane >> 4;
    float mymax[4] = {-1e30f, -1e30f, -1e30f, -1e30f};
    #pragma unroll
    for (int mt = 0; mt < 2; ++mt) {
        bf16x8 af = *(bf16x8*)&As[(2 * wave + mt) * 16 + lr][lg * 8];
        #pragma unroll
        for (int nt = 0; nt < 7; ++nt) {
            bf16x8 bfp = *(bf16x8*)&Pj[nt * 16 + lr][lg * 8];
            f32x4 d = (f32x4){0.f, 0.f, 0.f, 0.f};
            d = __builtin_amdgcn_mfma_f32_16x16x32_bf16(af, bfp, d, 0, 0, 0);
            if (!(nt == 6 && lr >= 14)) {
                #pragma unroll
                for (int r = 0; r < 4; ++r) mymax[r] = fmaxf(mymax[r], d[r]);
            }
        }
    }
    #pragma unroll
    for (int r = 0; r < 4; ++r) {
        float v = mymax[r];
        v = fmaxf(v, __shfl_xor(v, 1));
        v = fmaxf(v, __shfl_xor(v, 2));
        v = fmaxf(v, __shfl_xor(v, 4));
        v = fmaxf(v, __shfl_xor(v, 8));
        v = fmaxf(v, __shfl_xor(v, 32));
        mymax[r] = v;
    }
    if (lane == 0 || lane == 16) {
        int hb = (lane >> 4) & 1;
        #pragma unroll
        for (int r = 0; r < 4; ++r) wmax[wave][4 * hb + r] = mymax[r];
    }
    __syncthreads();
    if (tid < 8) {
        float m = fmaxf(fmaxf(wmax[0][tid], wmax[1][tid]), fmaxf(wmax[2][tid], wmax[3][tid]));
        partial[blockIdx.x * 8 + tid] = m * c_dn;
    }
}

// ---------------- kreduce: kmaxf[bh] = max over 512 partials ----------------
__global__ __launch_bounds__(256) void kreduce_kernel(const float* __restrict__ partial,
                                                      float* __restrict__ kmaxf) {
    __shared__ float wred[4];
    int bh = blockIdx.x, b = bh >> 3, h = bh & 7;
    int tid = threadIdx.x;
    float m = fmaxf(partial[(b * 512 + tid) * 8 + h], partial[(b * 512 + 256 + tid) * 8 + h]);
    #pragma unroll
    for (int off = 32; off; off >>= 1) m = fmaxf(m, __shfl_xor(m, off));
    if ((tid & 63) == 0) wred[tid >> 6] = m;
    __syncthreads();
    if (tid == 0)
        kmaxf[bh] = fmaxf(fmaxf(wred[0], wred[1]), fmaxf(wred[2], wred[3]));
}

// ---------------- ctxg: fused kp + ctx accumulation (one bh per blockIdx.y) ----------------
__global__ __launch_bounds__(256) void ctxg_kernel(const unsigned short* __restrict__ k,
                                                   const unsigned short* __restrict__ v,
                                                   const float* __restrict__ proj,
                                                   const float* __restrict__ kmaxf,
                                                   float* __restrict__ ctx) {
    __shared__ __align__(16) char pool[34816];   // As[128][40] union KpT[128][136]
    unsigned short (*As)[40] = (unsigned short(*)[40])pool;
    unsigned short (*KpT)[136] = (unsigned short(*)[136])pool;
    __shared__ unsigned short Pj[112][40];
    __shared__ unsigned short VsT[48][136];
    __shared__ float dg[128];
    int tid = threadIdx.x;
    int bh = blockIdx.y, b = bh >> 3, h = bh & 7;
    int n_base = blockIdx.x * 512;
    float mx = kmaxf[bh];
    // pjT
    for (int idx = tid; idx < 112 * 8; idx += 256) {
        int m = idx >> 3, f4 = idx & 7;
        if (m < NB) {
            float4 va = *(const float4*)(proj + m * 32 + f4 * 4);
            bf16x4 pk = {(short)f2b(va.x), (short)f2b(va.y), (short)f2b(va.z), (short)f2b(va.w)};
            *(bf16x4*)&Pj[m][f4 * 4] = pk;
        } else {
            *(bf16x4*)&Pj[m][f4 * 4] = (bf16x4){0, 0, 0, 0};
        }
    }
    // KpT pad rows 112..127 zero (outside As byte range; persists)
    for (int idx = tid; idx < 16 * 136; idx += 256) KpT[112 + idx / 136][idx % 136] = 0;
    // VsT rows 32..47: ones row + zero pad (persist across sub-iters)
    for (int idx = tid; idx < 16 * 128; idx += 256) {
        int rr = 32 + (idx >> 7), nn = idx & 127;
        VsT[rr][nn] = (rr == 32) ? (unsigned short)0x3F80 : (unsigned short)0;
    }
    int wave = tid >> 6, lane = tid & 63, lr = lane & 15, lg = lane >> 4;
    int arow = tid >> 1, ahalf = tid & 1;
    f32x4 ctxacc[2][3];
    #pragma unroll
    for (int mt = 0; mt < 2; ++mt)
        #pragma unroll
        for (int nt = 0; nt < 3; ++nt) ctxacc[mt][nt] = (f32x4){0.f, 0.f, 0.f, 0.f};

    for (int ni = 0; ni < 4; ++ni) {
        int n0 = n_base + ni * 128;
        // stage k slice (bf16 copy) + diag
        {
            const unsigned short* kp_ = k + ((size_t)(b * NSEQ + n0 + arow) * 256 + h * 32 + ahalf * 16);
            bf16x8 k0 = *(const bf16x8*)kp_;
            bf16x8 k1 = *(const bf16x8*)(kp_ + 8);
            *(bf16x8*)&As[arow][ahalf * 16] = k0;
            *(bf16x8*)&As[arow][ahalf * 16 + 8] = k1;
            float ssq = 0.f;
            #pragma unroll
            for (int e = 0; e < 8; ++e) {
                float a = b2f((unsigned short)k0[e]), bb = b2f((unsigned short)k1[e]);
                ssq += a * a + bb * bb;
            }
            ssq += __shfl_xor(ssq, 1);
            if (ahalf == 0) dg[arow] = ssq * c_diagf;
        }
        // stage v transposed
        #pragma unroll
        for (int it = 0; it < 4; ++it) {
            int idx = it * 256 + tid;
            int nn = idx >> 3, f4 = idx & 7;
            bf16x4 vv = *(const bf16x4*)(v + ((size_t)(b * NSEQ + n0 + nn) * 256 + h * 32 + f4 * 4));
            VsT[f4 * 4 + 0][nn] = (unsigned short)vv[0];
            VsT[f4 * 4 + 1][nn] = (unsigned short)vv[1];
            VsT[f4 * 4 + 2][nn] = (unsigned short)vv[2];
            VsT[f4 * 4 + 3][nn] = (unsigned short)vv[3];
        }
        __syncthreads();
        // xd MFMA -> regs
        f32x4 xds[2][7];
        #pragma unroll
        for (int mt = 0; mt < 2; ++mt) {
            bf16x8 af = *(bf16x8*)&As[(2 * wave + mt) * 16 + lr][lg * 8];
            #pragma unroll
            for (int nt = 0; nt < 7; ++nt) {
                bf16x8 bfp = *(bf16x8*)&Pj[nt * 16 + lr][lg * 8];
                f32x4 d = (f32x4){0.f, 0.f, 0.f, 0.f};
                xds[mt][nt] = __builtin_amdgcn_mfma_f32_16x16x32_bf16(af, bfp, d, 0, 0, 0);
            }
        }
        __syncthreads();   // As reads done; safe to overwrite via KpT
        // exp -> KpT (bf16), transposed write
        #pragma unroll
        for (int mt = 0; mt < 2; ++mt)
            #pragma unroll
            for (int nt = 0; nt < 7; ++nt) {
                int m = nt * 16 + lr;
                #pragma unroll
                for (int r = 0; r < 4; ++r) {
                    int nn = (2 * wave + mt) * 16 + lg * 4 + r;
                    float kpv = (m < NB) ? c_ratio * (__expf(xds[mt][nt][r] * c_dn - dg[nn] - mx) + 1e-4f) : 0.f;
                    KpT[m][nn] = f2b(kpv);
                }
            }
        __syncthreads();
        // ctx MFMA accumulate: ctx[m][c] += sum_n kp[n][m]*vext[n][c]
        #pragma unroll
        for (int ks = 0; ks < 4; ++ks)
            #pragma unroll
            for (int mt = 0; mt < 2; ++mt) {
                bf16x8 af2 = *(bf16x8*)&KpT[(2 * wave + mt) * 16 + lr][ks * 32 + lg * 8];
                #pragma unroll
                for (int nt = 0; nt < 3; ++nt) {
                    bf16x8 bf2 = *(bf16x8*)&VsT[nt * 16 + lr][ks * 32 + lg * 8];
                    ctxacc[mt][nt] = __builtin_amdgcn_mfma_f32_16x16x32_bf16(af2, bf2, ctxacc[mt][nt], 0, 0, 0);
                }
            }
        __syncthreads();
    }
    #pragma unroll
    for (int mt = 0; mt < 2; ++mt)
        #pragma unroll
        for (int nt = 0; nt < 3; ++nt)
            #pragma unroll
            for (int r = 0; r < 4; ++r) {
                int m = (2 * wave + mt) * 16 + lg * 4 + r;
                atomicAdd(&ctx[((size_t)bh * 128 + m) * 48 + nt * 16 + lr], ctxacc[mt][nt][r]);
            }
}

// ---------------- og: fused qp + output (one bh per 64 blocks) ----------------
__global__ __launch_bounds__(256) void og_kernel(const unsigned short* __restrict__ q,
                                                 const float* __restrict__ proj,
                                                 const float* __restrict__ ctx,
                                                 unsigned short* __restrict__ o) {
    __shared__ __align__(16) char pool[34816];   // As[128][40] union Qp[128][136]
    unsigned short (*As)[40] = (unsigned short(*)[40])pool;
    unsigned short (*Qp)[136] = (unsigned short(*)[136])pool;
    __shared__ unsigned short Pj[112][40];
    __shared__ unsigned short CsT[48][136];
    __shared__ float dg[128];
    int tid = threadIdx.x;
    int bh = blockIdx.x >> 6, b = bh >> 3, h = bh & 7;
    int n0 = (blockIdx.x & 63) * 128;
    for (int idx = tid; idx < 112 * 8; idx += 256) {
        int m = idx >> 3, f4 = idx & 7;
        if (m < NB) {
            float4 va = *(const float4*)(proj + m * 32 + f4 * 4);
            bf16x4 pk = {(short)f2b(va.x), (short)f2b(va.y), (short)f2b(va.z), (short)f2b(va.w)};
            *(bf16x4*)&Pj[m][f4 * 4] = pk;
        } else {
            *(bf16x4*)&Pj[m][f4 * 4] = (bf16x4){0, 0, 0, 0};
        }
    }
    // stage ctx^T (48 x 128)
    for (int idx = tid; idx < 128 * 12; idx += 256) {
        int m = idx / 12, c4 = idx - m * 12;
        float4 cv = *(const float4*)(ctx + ((size_t)bh * 128 + m) * 48 + c4 * 4);
        CsT[c4 * 4 + 0][m] = f2b(cv.x);
        CsT[c4 * 4 + 1][m] = f2b(cv.y);
        CsT[c4 * 4 + 2][m] = f2b(cv.z);
        CsT[c4 * 4 + 3][m] = f2b(cv.w);
    }
    int arow = tid >> 1, ahalf = tid & 1;
    {
        const unsigned short* qp_ = q + ((size_t)(b * NSEQ + n0 + arow) * 256 + h * 32 + ahalf * 16);
        bf16x8 q0 = *(const bf16x8*)qp_;
        bf16x8 q1 = *(const bf16x8*)(qp_ + 8);
        *(bf16x8*)&As[arow][ahalf * 16] = q0;
        *(bf16x8*)&As[arow][ahalf * 16 + 8] = q1;
        float ssq = 0.f;
        #pragma unroll
        for (int e = 0; e < 8; ++e) {
            float a = b2f((unsigned short)q0[e]), bb = b2f((unsigned short)q1[e]);
            ssq += a * a + bb * bb;
        }
        ssq += __shfl_xor(ssq, 1);
        if (ahalf == 0) dg[arow] = ssq * c_diagf;
    }
    __syncthreads();
    int wave = tid >> 6, lane = tid & 63, lr = lane & 15, lg = lane >> 4;
    // xd MFMA -> regs
    f32x4 xds[2][7];
    #pragma unroll
    for (int mt = 0; mt < 2; ++mt) {
        bf16x8 af = *(bf16x8*)&As[(2 * wave + mt) * 16 + lr][lg * 8];
        #pragma unroll
        for (int nt = 0; nt < 7; ++nt) {
            bf16x8 bfp = *(bf16x8*)&Pj[nt * 16 + lr][lg * 8];
            f32x4 d = (f32x4){0.f, 0.f, 0.f, 0.f};
            xds[mt][nt] = __builtin_amdgcn_mfma_f32_16x16x32_bf16(af, bfp, d, 0, 0, 0);
        }
    }
    // per-row max (raw dot), mask pad cols
    float rmax[2][4];
    #pragma unroll
    for (int mt = 0; mt < 2; ++mt)
        #pragma unroll
        for (int r = 0; r < 4; ++r) {
            float mv = -1e30f;
            #pragma unroll
            for (int nt = 0; nt < 7; ++nt)
                if (!(nt == 6 && lr >= 14)) mv = fmaxf(mv, xds[mt][nt][r]);
            mv = fmaxf(mv, __shfl_xor(mv, 1));
            mv = fmaxf(mv, __shfl_xor(mv, 2));
            mv = fmaxf(mv, __shfl_xor(mv, 4));
            mv = fmaxf(mv, __shfl_xor(mv, 8));
            rmax[mt][r] = mv;
        }
    __syncthreads();   // As reads done; safe to write Qp over it
    #pragma unroll
    for (int mt = 0; mt < 2; ++mt)
        #pragma unroll
        for (int r = 0; r < 4; ++r) {
            int row = (2 * wave + mt) * 16 + lg * 4 + r;
            #pragma unroll
            for (int nt = 0; nt < 7; ++nt) {
                int m = nt * 16 + lr;
                float qpv = (m < NB)
                    ? c_ratio * (__expf((xds[mt][nt][r] - rmax[mt][r]) * c_dn - dg[row]) + 1e-4f)
                    : 0.f;
                Qp[row][m] = f2b(qpv);
            }
            Qp[row][112 + lr] = 0;   // zero pad cols 112..127
        }
    __syncthreads();
    // o MFMA: [128 rows] x [48 cols] over K=128
    f32x4 oacc[2][3];
    #pragma unroll
    for (int mt = 0; mt < 2; ++mt)
        #pragma unroll
        for (int nt = 0; nt < 3; ++nt) oacc[mt][nt] = (f32x4){0.f, 0.f, 0.f, 0.f};
    #pragma unroll
    for (int ks = 0; ks < 4; ++ks)
        #pragma unroll
        for (int mt = 0; mt < 2; ++mt) {
            bf16x8 af2 = *(bf16x8*)&Qp[(2 * wave + mt) * 16 + lr][ks * 32 + lg * 8];
            #pragma unroll
            for (int nt = 0; nt < 3; ++nt) {
                bf16x8 bf2 = *(bf16x8*)&CsT[nt * 16 + lr][ks * 32 + lg * 8];
                oacc[mt][nt] = __builtin_amdgcn_mfma_f32_16x16x32_bf16(af2, bf2, oacc[mt][nt], 0, 0, 0);
            }
        }
    #pragma unroll
    for (int mt = 0; mt < 2; ++mt)
        #pragma unroll
        for (int r = 0; r < 4; ++r) {
            int row = (2 * wave + mt) * 16 + lg * 4 + r;
            int n = n0 + row;
            float den = __shfl(oacc[mt][2][r], lane & 48);
            float inv = 1.0f / den;
            size_t base = (size_t)(b * NSEQ + n) * 256 + h * 32;
            o[base + lr] = f2b(oacc[mt][0][r] * inv);
            o[base + 16 + lr] = f2b(oacc[mt][1][r] * inv);
        }
}

extern "C" void kernel_launch(void* const* d_in, const int* in_sizes, int n_in,
                              void* d_out, int out_size, void* d_ws, size_t ws_size,
                              hipStream_t stream) {
    const float* x = (const float*)d_in[0];
    const float* proj = (const float*)d_in[1];
    const float* ln1_g = (const float*)d_in[2];
    const float* ln1_b = (const float*)d_in[3];
    const float* Wq = (const float*)d_in[4];
    const float* bq = (const float*)d_in[5];
    const float* Wk = (const float*)d_in[6];
    const float* bk = (const float*)d_in[7];
    const float* Wv = (const float*)d_in[8];
    const float* bv = (const float*)d_in[9];
    const float* Wo = (const float*)d_in[10];
    const float* bo = (const float*)d_in[11];
    const float* ln2_g = (const float*)d_in[12];
    const float* ln2_b = (const float*)d_in[13];
    const float* Wf1 = (const float*)d_in[14];
    const float* bf1 = (const float*)d_in[15];
    const float* Wf2 = (const float*)d_in[16];
    const float* bf2 = (const float*)d_in[17];

    float* h = (float*)d_out;
    const size_t ACT = (size_t)MROWS * DIM;          // 8,388,608 elements
    // all intermediates bf16
    unsigned short* y = (unsigned short*)d_ws;
    unsigned short* q = y + ACT;
    unsigned short* k = q + ACT;
    unsigned short* v = k + ACT;
    unsigned short* mid = v + ACT;                   // [32768][1024] bf16 = 4*ACT shorts
    float* ctx = (float*)(mid + 4 * ACT);            // [32][128][48] f32
    float* kmaxf = ctx + (size_t)BH * 128 * 48;
    float* partial = kmaxf + 32;                     // 2048*8 floats
    unsigned short* wt = (unsigned short*)(partial + 2048 * 8);
    unsigned short* o = y;                           // o aliases y (dead between QKV and ln2)

    // per-layer wt stride: 4*(256*256) + 2*(256*1024) = 786432 bf16
    const int WT_L = 786432;
    const int CTXN = BH * 128 * 48;

    copy4_kernel<<<(int)(ACT / 4) / 256, 256, 0, stream>>>((const float4*)x, (float4*)h, (int)(ACT / 4));

    // pre-transpose+convert all weights (all 4 layers)
    wt_kernel<<<dim3(8, 8, 4), 256, 0, stream>>>(Wq, wt + 0, 256, 256, WT_L);
    wt_kernel<<<dim3(8, 8, 4), 256, 0, stream>>>(Wk, wt + 65536, 256, 256, WT_L);
    wt_kernel<<<dim3(8, 8, 4), 256, 0, stream>>>(Wv, wt + 131072, 256, 256, WT_L);
    wt_kernel<<<dim3(8, 8, 4), 256, 0, stream>>>(Wo, wt + 196608, 256, 256, WT_L);
    wt_kernel<<<dim3(8, 32, 4), 256, 0, stream>>>(Wf1, wt + 262144, 256, 1024, WT_L);
    wt_kernel<<<dim3(32, 8, 4), 256, 0, stream>>>(Wf2, wt + 524288, 1024, 256, WT_L);

    for (int i = 0; i < 4; ++i) {
        const float* proj_i = proj + (size_t)i * NB * DHEAD;
        const unsigned short* wl = wt + (size_t)i * WT_L;
        // --- attention ---
        ln_kernel<<<MROWS / 4, 256, 0, stream>>>(h, ln1_g + i * DIM, ln1_b + i * DIM, y);
        dim3 g256(2, 256);
        gemm_mfma<0><<<g256, 256, 0, stream>>>(y, wl + 0, bq + i * INNER, nullptr, q, INNER, DIM);
        gemm_mfma<0><<<g256, 256, 0, stream>>>(y, wl + 65536, bk + i * INNER, nullptr, k, INNER, DIM);
        gemm_mfma<0><<<g256, 256, 0, stream>>>(y, wl + 131072, bv + i * INNER, nullptr, v, INNER, DIM);

        zero_kernel<<<(CTXN + 255) / 256, 256, 0, stream>>>(ctx, CTXN);
        kmaxg_kernel<<<2048, 256, 0, stream>>>(k, proj_i, partial);
        kreduce_kernel<<<BH, 256, 0, stream>>>(partial, kmaxf);
        ctxg_kernel<<<dim3(16, BH), 256, 0, stream>>>(k, v, proj_i, kmaxf, ctx);
        og_kernel<<<BH * 64, 256, 0, stream>>>(q, proj_i, ctx, o);

        gemm_mfma<1><<<g256, 256, 0, stream>>>(o, wl + 196608, bo + i * DIM, h, h, DIM, INNER);

        // --- FFN ---
        ln_kernel<<<MROWS / 4, 256, 0, stream>>>(h, ln2_g + i * DIM, ln2_b + i * DIM, y);
        gemm_mfma<2><<<dim3(8, 256), 256, 0, stream>>>(y, wl + 262144, bf1 + i * FFDIM, nullptr, mid, FFDIM, DIM);
        gemm_mfma<1><<<dim3(2, 256), 256, 0, stream>>>(mid, wl + 524288, bf2 + i * DIM, h, h, DIM, FFDIM);
    }
}

// Round 9
// 953.758 us; speedup vs baseline: 8.3977x; 1.0088x over previous
//
#include <hip/hip_runtime.h>
#include <math.h>

#define NSEQ 8192
#define BATCH 4
#define DIM 256
#define HEADS 8
#define DHEAD 32
#define NB 110
#define INNER 256
#define FFDIM 1024
#define MROWS (BATCH * NSEQ)   // 32768 rows
#define BH (BATCH * HEADS)     // 32

typedef __attribute__((ext_vector_type(8))) short bf16x8;
typedef __attribute__((ext_vector_type(4))) short bf16x4;
typedef __attribute__((ext_vector_type(4))) float f32x4;

typedef __attribute__((address_space(1))) const void* gas_cvp;
typedef __attribute__((address_space(3))) void* las_vp;

constexpr float c_dn = 0.42044820762685725f;     // 32^-0.25
constexpr float c_diagf = 0.08838834764831845f;  // 0.5*dn*dn
constexpr float c_ratio = 0.09534625892455922f;  // 110^-0.5

__device__ __forceinline__ unsigned short f2b(float f) {
    unsigned u = __float_as_uint(f);
    unsigned r = (u + 0x7FFFu + ((u >> 16) & 1u)) >> 16;
    return (unsigned short)r;
}
__device__ __forceinline__ float b2f(unsigned short u) {
    return __uint_as_float((unsigned)u << 16);
}

// ---------------- util ----------------
__global__ __launch_bounds__(256) void copy4_kernel(const float4* __restrict__ src,
                                                    float4* __restrict__ dst, int n4) {
    int i = blockIdx.x * 256 + threadIdx.x;
    if (i < n4) dst[i] = src[i];
}
__global__ __launch_bounds__(256) void zero_kernel(float* __restrict__ p, int n) {
    int i = blockIdx.x * 256 + threadIdx.x;
    if (i < n) p[i] = 0.0f;
}

// ---------------- LayerNorm: f32 in -> bf16 out ----------------
__global__ __launch_bounds__(256) void ln_kernel(const float* __restrict__ x,
                                                 const float* __restrict__ g,
                                                 const float* __restrict__ bta,
                                                 unsigned short* __restrict__ y) {
    int wave = threadIdx.x >> 6, lane = threadIdx.x & 63;
    int row = blockIdx.x * 4 + wave;
    const float* xr = x + (size_t)row * DIM;
    float4 v = *(const float4*)(xr + lane * 4);
    float s = v.x + v.y + v.z + v.w;
    float sq = v.x * v.x + v.y * v.y + v.z * v.z + v.w * v.w;
    #pragma unroll
    for (int off = 32; off; off >>= 1) {
        s += __shfl_xor(s, off);
        sq += __shfl_xor(sq, off);
    }
    float mean = s * (1.0f / DIM);
    float var = sq * (1.0f / DIM) - mean * mean;
    float rstd = rsqrtf(var + 1e-5f);
    float4 gg = *(const float4*)(g + lane * 4);
    float4 bb = *(const float4*)(bta + lane * 4);
    bf16x4 o;
    o[0] = (short)f2b((v.x - mean) * rstd * gg.x + bb.x);
    o[1] = (short)f2b((v.y - mean) * rstd * gg.y + bb.y);
    o[2] = (short)f2b((v.z - mean) * rstd * gg.z + bb.z);
    o[3] = (short)f2b((v.w - mean) * rstd * gg.w + bb.w);
    *(bf16x4*)(y + (size_t)row * DIM + lane * 4) = o;
}

// ---------------- weight transpose+convert: out[l][n][k] = bf16(in[l][k][n]) ----------------
__global__ __launch_bounds__(256) void wt_kernel(const float* __restrict__ in,
                                                 unsigned short* __restrict__ out,
                                                 int K, int Nn, int lstride) {
    __shared__ float t32[32][33];
    int l = blockIdx.z;
    const float* inp = in + (size_t)l * K * Nn;
    unsigned short* outp = out + (size_t)l * lstride;
    int k0 = blockIdx.x * 32, n0 = blockIdx.y * 32;
    int tx = threadIdx.x & 31, ty = threadIdx.x >> 5;
    #pragma unroll
    for (int i = 0; i < 4; ++i)
        t32[ty + i * 8][tx] = inp[(size_t)(k0 + ty + i * 8) * Nn + n0 + tx];
    __syncthreads();
    #pragma unroll
    for (int i = 0; i < 4; ++i) {
        int r = ty + i * 8;  // n within tile
        outp[(size_t)(n0 + r) * K + k0 + tx] = f2b(t32[tx][r]);
    }
}

// ---------------- bf16 MFMA GEMM with global_load_lds staging (m97 pattern) ----------------
// C[M,N] = A[M,K](bf16) @ Wt[N,K]^T(bf16) + epilogue
// EPI 0: +bias -> bf16 out   EPI 1: +bias+res(f32) -> f32 out   EPI 2: gelu(+bias) -> bf16 out
// Tile = 128 rows x 32 shorts = 512 x 16B granules. Granule f = wave*128 + j*64 + lane, j<2.
// row = f>>2; source chunk = (f&3) ^ ((row>>1)&3)  (XOR swizzle on SOURCE + READ, dest linear).
template <int EPI>
__global__ __launch_bounds__(256) void gemm_mfma(const unsigned short* __restrict__ A,
                                                 const unsigned short* __restrict__ Wt,
                                                 const float* __restrict__ bias,
                                                 const float* __restrict__ res,
                                                 void* __restrict__ Cv,
                                                 int Nn, int K) {
    __shared__ unsigned short As[128 * 32];
    __shared__ unsigned short Bs[128 * 32];
    int tid = threadIdx.x;
    int m0 = blockIdx.y * 128, n0 = blockIdx.x * 128;
    int wave = tid >> 6, lane = tid & 63;
    int wm = (wave >> 1) * 64, wn = (wave & 1) * 64;
    int lr = lane & 15, lg = lane >> 4;
    f32x4 acc[4][4];
    #pragma unroll
    for (int i = 0; i < 4; ++i)
        #pragma unroll
        for (int j = 0; j < 4; ++j) acc[i][j] = (f32x4){0.f, 0.f, 0.f, 0.f};

    // staging geometry: 512 granules/tile; granule f = wave*128 + j*64 + lane (j<2)
    int rowS[2], chS[2];
    #pragma unroll
    for (int j = 0; j < 2; ++j) {
        int f = wave * 128 + j * 64 + lane;
        rowS[j] = f >> 2;                                 // 0..127
        chS[j] = ((f & 3) ^ ((rowS[j] >> 1) & 3)) * 8;    // shorts offset within row
    }
    // per-lane read offsets (shorts), XOR-swizzled chunk
    int rdA[4], rdB[4];
    #pragma unroll
    for (int i = 0; i < 4; ++i) {
        int ra = wm + i * 16 + lr;
        rdA[i] = ra * 32 + (lg ^ ((ra >> 1) & 3)) * 8;
        int rb = wn + i * 16 + lr;
        rdB[i] = rb * 32 + (lg ^ ((rb >> 1) & 3)) * 8;
    }

    for (int kt = 0; kt < K; kt += 32) {
        #pragma unroll
        for (int j = 0; j < 2; ++j) {
            const unsigned short* srcA = A + (size_t)(m0 + rowS[j]) * K + kt + chS[j];
            __builtin_amdgcn_global_load_lds((gas_cvp)srcA,
                                             (las_vp)(As + wave * 1024 + j * 512), 16, 0, 0);
            const unsigned short* srcB = Wt + (size_t)(n0 + rowS[j]) * K + kt + chS[j];
            __builtin_amdgcn_global_load_lds((gas_cvp)srcB,
                                             (las_vp)(Bs + wave * 1024 + j * 512), 16, 0, 0);
        }
        __syncthreads();
        bf16x8 af[4], bfv[4];
        #pragma unroll
        for (int i = 0; i < 4; ++i) af[i] = *(bf16x8*)&As[rdA[i]];
        #pragma unroll
        for (int j = 0; j < 4; ++j) bfv[j] = *(bf16x8*)&Bs[rdB[j]];
        #pragma unroll
        for (int i = 0; i < 4; ++i)
            #pragma unroll
            for (int j = 0; j < 4; ++j)
                acc[i][j] = __builtin_amdgcn_mfma_f32_16x16x32_bf16(af[i], bfv[j], acc[i][j], 0, 0, 0);
        __syncthreads();
    }
    #pragma unroll
    for (int i = 0; i < 4; ++i) {
        #pragma unroll
        for (int j = 0; j < 4; ++j) {
            int col = n0 + wn + j * 16 + lr;
            float bv = bias[col];
            #pragma unroll
            for (int r = 0; r < 4; ++r) {
                int row = m0 + wm + i * 16 + lg * 4 + r;
                float c = acc[i][j][r] + bv;
                if (EPI == 1) {
                    c += res[(size_t)row * Nn + col];
                    ((float*)Cv)[(size_t)row * Nn + col] = c;
                } else if (EPI == 2) {
                    float u = c;
                    float t = 1.5957691216057308f * (u + 0.044715f * u * u * u);  // 2*0.79788456*(...)
                    float gv = u / (1.0f + __expf(-t));
                    ((unsigned short*)Cv)[(size_t)row * Nn + col] = f2b(gv);
                } else {
                    ((unsigned short*)Cv)[(size_t)row * Nn + col] = f2b(c);
                }
            }
        }
    }
}

// ---------------- kmaxg: per-block partial max over n,m of dn*(k . proj_m); NO atomics ----------------
__global__ __launch_bounds__(256) void kmaxg_kernel(const unsigned short* __restrict__ k,
                                                    const float* __restrict__ proj,
                                                    float* __restrict__ partial) {
    __shared__ unsigned short As[128][40];
    __shared__ unsigned short Pj[112][40];
    __shared__ float wmax[4][8];
    int tid = threadIdx.x;
    int r0 = blockIdx.x * 128;     // flat row in [262144] = (b*8192+n)*8+h
    for (int idx = tid; idx < 112 * 8; idx += 256) {
        int m = idx >> 3, f4 = idx & 7;
        if (m < NB) {
            float4 va = *(const float4*)(proj + m * 32 + f4 * 4);
            bf16x4 pk = {(short)f2b(va.x), (short)f2b(va.y), (short)f2b(va.z), (short)f2b(va.w)};
            *(bf16x4*)&Pj[m][f4 * 4] = pk;
        } else {
            *(bf16x4*)&Pj[m][f4 * 4] = (bf16x4){0, 0, 0, 0};
        }
    }
    int arow = tid >> 1, ahalf = tid & 1;
    const unsigned short* ap = k + (size_t)(r0 + arow) * 32 + ahalf * 16;
    *(bf16x8*)&As[arow][ahalf * 16] = *(const bf16x8*)ap;
    *(bf16x8*)&As[arow][ahalf * 16 + 8] = *(const bf16x8*)(ap + 8);
    __syncthreads();
    int wave = tid >> 6, lane = tid & 63, lr = lane & 15, lg = lane >> 4;
    float mymax[4] = {-1e30f, -1e30f, -1e30f, -1e30f};
    #pragma unroll
    for (int mt = 0; mt < 2; ++mt) {
        bf16x8 af = *(bf16x8*)&As[(2 * wave + mt) * 16 + lr][lg * 8];
        #pragma unroll
        for (int nt = 0; nt < 7; ++nt) {
            bf16x8 bfp = *(bf16x8*)&Pj[nt * 16 + lr][lg * 8];
            f32x4 d = (f32x4){0.f, 0.f, 0.f, 0.f};
            d = __builtin_amdgcn_mfma_f32_16x16x32_bf16(af, bfp, d, 0, 0, 0);
            if (!(nt == 6 && lr >= 14)) {
                #pragma unroll
                for (int r = 0; r < 4; ++r) mymax[r] = fmaxf(mymax[r], d[r]);
            }
        }
    }
    #pragma unroll
    for (int r = 0; r < 4; ++r) {
        float v = mymax[r];
        v = fmaxf(v, __shfl_xor(v, 1));
        v = fmaxf(v, __shfl_xor(v, 2));
        v = fmaxf(v, __shfl_xor(v, 4));
        v = fmaxf(v, __shfl_xor(v, 8));
        v = fmaxf(v, __shfl_xor(v, 32));
        mymax[r] = v;
    }
    if (lane == 0 || lane == 16) {
        int hb = (lane >> 4) & 1;
        #pragma unroll
        for (int r = 0; r < 4; ++r) wmax[wave][4 * hb + r] = mymax[r];
    }
    __syncthreads();
    if (tid < 8) {
        float m = fmaxf(fmaxf(wmax[0][tid], wmax[1][tid]), fmaxf(wmax[2][tid], wmax[3][tid]));
        partial[blockIdx.x * 8 + tid] = m * c_dn;
    }
}

// ---------------- kreduce: kmaxf[bh] = max over 512 partials ----------------
__global__ __launch_bounds__(256) void kreduce_kernel(const float* __restrict__ partial,
                                                      float* __restrict__ kmaxf) {
    __shared__ float wred[4];
    int bh = blockIdx.x, b = bh >> 3, h = bh & 7;
    int tid = threadIdx.x;
    float m = fmaxf(partial[(b * 512 + tid) * 8 + h], partial[(b * 512 + 256 + tid) * 8 + h]);
    #pragma unroll
    for (int off = 32; off; off >>= 1) m = fmaxf(m, __shfl_xor(m, off));
    if ((tid & 63) == 0) wred[tid >> 6] = m;
    __syncthreads();
    if (tid == 0)
        kmaxf[bh] = fmaxf(fmaxf(wred[0], wred[1]), fmaxf(wred[2], wred[3]));
}

// ---------------- ctxg: fused kp + ctx accumulation (one bh per blockIdx.y) ----------------
__global__ __launch_bounds__(256) void ctxg_kernel(const unsigned short* __restrict__ k,
                                                   const unsigned short* __restrict__ v,
                                                   const float* __restrict__ proj,
                                                   const float* __restrict__ kmaxf,
                                                   float* __restrict__ ctx) {
    __shared__ __align__(16) char pool[34816];   // As[128][40] union KpT[128][136]
    unsigned short (*As)[40] = (unsigned short(*)[40])pool;
    unsigned short (*KpT)[136] = (unsigned short(*)[136])pool;
    __shared__ unsigned short Pj[112][40];
    __shared__ unsigned short VsT[48][136];
    __shared__ float dg[128];
    int tid = threadIdx.x;
    int bh = blockIdx.y, b = bh >> 3, h = bh & 7;
    int n_base = blockIdx.x * 512;
    float mx = kmaxf[bh];
    // pjT
    for (int idx = tid; idx < 112 * 8; idx += 256) {
        int m = idx >> 3, f4 = idx & 7;
        if (m < NB) {
            float4 va = *(const float4*)(proj + m * 32 + f4 * 4);
            bf16x4 pk = {(short)f2b(va.x), (short)f2b(va.y), (short)f2b(va.z), (short)f2b(va.w)};
            *(bf16x4*)&Pj[m][f4 * 4] = pk;
        } else {
            *(bf16x4*)&Pj[m][f4 * 4] = (bf16x4){0, 0, 0, 0};
        }
    }
    // KpT pad rows 112..127 zero (outside As byte range; persists)
    for (int idx = tid; idx < 16 * 136; idx += 256) KpT[112 + idx / 136][idx % 136] = 0;
    // VsT rows 32..47: ones row + zero pad (persist across sub-iters)
    for (int idx = tid; idx < 16 * 128; idx += 256) {
        int rr = 32 + (idx >> 7), nn = idx & 127;
        VsT[rr][nn] = (rr == 32) ? (unsigned short)0x3F80 : (unsigned short)0;
    }
    int wave = tid >> 6, lane = tid & 63, lr = lane & 15, lg = lane >> 4;
    int arow = tid >> 1, ahalf = tid & 1;
    f32x4 ctxacc[2][3];
    #pragma unroll
    for (int mt = 0; mt < 2; ++mt)
        #pragma unroll
        for (int nt = 0; nt < 3; ++nt) ctxacc[mt][nt] = (f32x4){0.f, 0.f, 0.f, 0.f};

    for (int ni = 0; ni < 4; ++ni) {
        int n0 = n_base + ni * 128;
        // stage k slice (bf16 copy) + diag
        {
            const unsigned short* kp_ = k + ((size_t)(b * NSEQ + n0 + arow) * 256 + h * 32 + ahalf * 16);
            bf16x8 k0 = *(const bf16x8*)kp_;
            bf16x8 k1 = *(const bf16x8*)(kp_ + 8);
            *(bf16x8*)&As[arow][ahalf * 16] = k0;
            *(bf16x8*)&As[arow][ahalf * 16 + 8] = k1;
            float ssq = 0.f;
            #pragma unroll
            for (int e = 0; e < 8; ++e) {
                float a = b2f((unsigned short)k0[e]), bb = b2f((unsigned short)k1[e]);
                ssq += a * a + bb * bb;
            }
            ssq += __shfl_xor(ssq, 1);
            if (ahalf == 0) dg[arow] = ssq * c_diagf;
        }
        // stage v transposed
        #pragma unroll
        for (int it = 0; it < 4; ++it) {
            int idx = it * 256 + tid;
            int nn = idx >> 3, f4 = idx & 7;
            bf16x4 vv = *(const bf16x4*)(v + ((size_t)(b * NSEQ + n0 + nn) * 256 + h * 32 + f4 * 4));
            VsT[f4 * 4 + 0][nn] = (unsigned short)vv[0];
            VsT[f4 * 4 + 1][nn] = (unsigned short)vv[1];
            VsT[f4 * 4 + 2][nn] = (unsigned short)vv[2];
            VsT[f4 * 4 + 3][nn] = (unsigned short)vv[3];
        }
        __syncthreads();
        // xd MFMA -> regs
        f32x4 xds[2][7];
        #pragma unroll
        for (int mt = 0; mt < 2; ++mt) {
            bf16x8 af = *(bf16x8*)&As[(2 * wave + mt) * 16 + lr][lg * 8];
            #pragma unroll
            for (int nt = 0; nt < 7; ++nt) {
                bf16x8 bfp = *(bf16x8*)&Pj[nt * 16 + lr][lg * 8];
                f32x4 d = (f32x4){0.f, 0.f, 0.f, 0.f};
                xds[mt][nt] = __builtin_amdgcn_mfma_f32_16x16x32_bf16(af, bfp, d, 0, 0, 0);
            }
        }
        __syncthreads();   // As reads done; safe to overwrite via KpT
        // exp -> KpT (bf16), transposed write
        #pragma unroll
        for (int mt = 0; mt < 2; ++mt)
            #pragma unroll
            for (int nt = 0; nt < 7; ++nt) {
                int m = nt * 16 + lr;
                #pragma unroll
                for (int r = 0; r < 4; ++r) {
                    int nn = (2 * wave + mt) * 16 + lg * 4 + r;
                    float kpv = (m < NB) ? c_ratio * (__expf(xds[mt][nt][r] * c_dn - dg[nn] - mx) + 1e-4f) : 0.f;
                    KpT[m][nn] = f2b(kpv);
                }
            }
        __syncthreads();
        // ctx MFMA accumulate: ctx[m][c] += sum_n kp[n][m]*vext[n][c]
        #pragma unroll
        for (int ks = 0; ks < 4; ++ks)
            #pragma unroll
            for (int mt = 0; mt < 2; ++mt) {
                bf16x8 af2 = *(bf16x8*)&KpT[(2 * wave + mt) * 16 + lr][ks * 32 + lg * 8];
                #pragma unroll
                for (int nt = 0; nt < 3; ++nt) {
                    bf16x8 bf2 = *(bf16x8*)&VsT[nt * 16 + lr][ks * 32 + lg * 8];
                    ctxacc[mt][nt] = __builtin_amdgcn_mfma_f32_16x16x32_bf16(af2, bf2, ctxacc[mt][nt], 0, 0, 0);
                }
            }
        __syncthreads();
    }
    #pragma unroll
    for (int mt = 0; mt < 2; ++mt)
        #pragma unroll
        for (int nt = 0; nt < 3; ++nt)
            #pragma unroll
            for (int r = 0; r < 4; ++r) {
                int m = (2 * wave + mt) * 16 + lg * 4 + r;
                atomicAdd(&ctx[((size_t)bh * 128 + m) * 48 + nt * 16 + lr], ctxacc[mt][nt][r]);
            }
}

// ---------------- og: fused qp + output (one bh per 64 blocks) ----------------
__global__ __launch_bounds__(256) void og_kernel(const unsigned short* __restrict__ q,
                                                 const float* __restrict__ proj,
                                                 const float* __restrict__ ctx,
                                                 unsigned short* __restrict__ o) {
    __shared__ __align__(16) char pool[34816];   // As[128][40] union Qp[128][136]
    unsigned short (*As)[40] = (unsigned short(*)[40])pool;
    unsigned short (*Qp)[136] = (unsigned short(*)[136])pool;
    __shared__ unsigned short Pj[112][40];
    __shared__ unsigned short CsT[48][136];
    __shared__ float dg[128];
    int tid = threadIdx.x;
    int bh = blockIdx.x >> 6, b = bh >> 3, h = bh & 7;
    int n0 = (blockIdx.x & 63) * 128;
    for (int idx = tid; idx < 112 * 8; idx += 256) {
        int m = idx >> 3, f4 = idx & 7;
        if (m < NB) {
            float4 va = *(const float4*)(proj + m * 32 + f4 * 4);
            bf16x4 pk = {(short)f2b(va.x), (short)f2b(va.y), (short)f2b(va.z), (short)f2b(va.w)};
            *(bf16x4*)&Pj[m][f4 * 4] = pk;
        } else {
            *(bf16x4*)&Pj[m][f4 * 4] = (bf16x4){0, 0, 0, 0};
        }
    }
    // stage ctx^T (48 x 128)
    for (int idx = tid; idx < 128 * 12; idx += 256) {
        int m = idx / 12, c4 = idx - m * 12;
        float4 cv = *(const float4*)(ctx + ((size_t)bh * 128 + m) * 48 + c4 * 4);
        CsT[c4 * 4 + 0][m] = f2b(cv.x);
        CsT[c4 * 4 + 1][m] = f2b(cv.y);
        CsT[c4 * 4 + 2][m] = f2b(cv.z);
        CsT[c4 * 4 + 3][m] = f2b(cv.w);
    }
    int arow = tid >> 1, ahalf = tid & 1;
    {
        const unsigned short* qp_ = q + ((size_t)(b * NSEQ + n0 + arow) * 256 + h * 32 + ahalf * 16);
        bf16x8 q0 = *(const bf16x8*)qp_;
        bf16x8 q1 = *(const bf16x8*)(qp_ + 8);
        *(bf16x8*)&As[arow][ahalf * 16] = q0;
        *(bf16x8*)&As[arow][ahalf * 16 + 8] = q1;
        float ssq = 0.f;
        #pragma unroll
        for (int e = 0; e < 8; ++e) {
            float a = b2f((unsigned short)q0[e]), bb = b2f((unsigned short)q1[e]);
            ssq += a * a + bb * bb;
        }
        ssq += __shfl_xor(ssq, 1);
        if (ahalf == 0) dg[arow] = ssq * c_diagf;
    }
    __syncthreads();
    int wave = tid >> 6, lane = tid & 63, lr = lane & 15, lg = lane >> 4;
    // xd MFMA -> regs
    f32x4 xds[2][7];
    #pragma unroll
    for (int mt = 0; mt < 2; ++mt) {
        bf16x8 af = *(bf16x8*)&As[(2 * wave + mt) * 16 + lr][lg * 8];
        #pragma unroll
        for (int nt = 0; nt < 7; ++nt) {
            bf16x8 bfp = *(bf16x8*)&Pj[nt * 16 + lr][lg * 8];
            f32x4 d = (f32x4){0.f, 0.f, 0.f, 0.f};
            xds[mt][nt] = __builtin_amdgcn_mfma_f32_16x16x32_bf16(af, bfp, d, 0, 0, 0);
        }
    }
    // per-row max (raw dot), mask pad cols
    float rmax[2][4];
    #pragma unroll
    for (int mt = 0; mt < 2; ++mt)
        #pragma unroll
        for (int r = 0; r < 4; ++r) {
            float mv = -1e30f;
            #pragma unroll
            for (int nt = 0; nt < 7; ++nt)
                if (!(nt == 6 && lr >= 14)) mv = fmaxf(mv, xds[mt][nt][r]);
            mv = fmaxf(mv, __shfl_xor(mv, 1));
            mv = fmaxf(mv, __shfl_xor(mv, 2));
            mv = fmaxf(mv, __shfl_xor(mv, 4));
            mv = fmaxf(mv, __shfl_xor(mv, 8));
            rmax[mt][r] = mv;
        }
    __syncthreads();   // As reads done; safe to write Qp over it
    #pragma unroll
    for (int mt = 0; mt < 2; ++mt)
        #pragma unroll
        for (int r = 0; r < 4; ++r) {
            int row = (2 * wave + mt) * 16 + lg * 4 + r;
            #pragma unroll
            for (int nt = 0; nt < 7; ++nt) {
                int m = nt * 16 + lr;
                float qpv = (m < NB)
                    ? c_ratio * (__expf((xds[mt][nt][r] - rmax[mt][r]) * c_dn - dg[row]) + 1e-4f)
                    : 0.f;
                Qp[row][m] = f2b(qpv);
            }
            Qp[row][112 + lr] = 0;   // zero pad cols 112..127
        }
    __syncthreads();
    // o MFMA: [128 rows] x [48 cols] over K=128
    f32x4 oacc[2][3];
    #pragma unroll
    for (int mt = 0; mt < 2; ++mt)
        #pragma unroll
        for (int nt = 0; nt < 3; ++nt) oacc[mt][nt] = (f32x4){0.f, 0.f, 0.f, 0.f};
    #pragma unroll
    for (int ks = 0; ks < 4; ++ks)
        #pragma unroll
        for (int mt = 0; mt < 2; ++mt) {
            bf16x8 af2 = *(bf16x8*)&Qp[(2 * wave + mt) * 16 + lr][ks * 32 + lg * 8];
            #pragma unroll
            for (int nt = 0; nt < 3; ++nt) {
                bf16x8 bf2 = *(bf16x8*)&CsT[nt * 16 + lr][ks * 32 + lg * 8];
                oacc[mt][nt] = __builtin_amdgcn_mfma_f32_16x16x32_bf16(af2, bf2, oacc[mt][nt], 0, 0, 0);
            }
        }
    #pragma unroll
    for (int mt = 0; mt < 2; ++mt)
        #pragma unroll
        for (int r = 0; r < 4; ++r) {
            int row = (2 * wave + mt) * 16 + lg * 4 + r;
            int n = n0 + row;
            float den = __shfl(oacc[mt][2][r], lane & 48);
            float inv = 1.0f / den;
            size_t base = (size_t)(b * NSEQ + n) * 256 + h * 32;
            o[base + lr] = f2b(oacc[mt][0][r] * inv);
            o[base + 16 + lr] = f2b(oacc[mt][1][r] * inv);
        }
}

extern "C" void kernel_launch(void* const* d_in, const int* in_sizes, int n_in,
                              void* d_out, int out_size, void* d_ws, size_t ws_size,
                              hipStream_t stream) {
    const float* x = (const float*)d_in[0];
    const float* proj = (const float*)d_in[1];
    const float* ln1_g = (const float*)d_in[2];
    const float* ln1_b = (const float*)d_in[3];
    const float* Wq = (const float*)d_in[4];
    const float* bq = (const float*)d_in[5];
    const float* Wk = (const float*)d_in[6];
    const float* bk = (const float*)d_in[7];
    const float* Wv = (const float*)d_in[8];
    const float* bv = (const float*)d_in[9];
    const float* Wo = (const float*)d_in[10];
    const float* bo = (const float*)d_in[11];
    const float* ln2_g = (const float*)d_in[12];
    const float* ln2_b = (const float*)d_in[13];
    const float* Wf1 = (const float*)d_in[14];
    const float* bf1 = (const float*)d_in[15];
    const float* Wf2 = (const float*)d_in[16];
    const float* bf2 = (const float*)d_in[17];

    float* h = (float*)d_out;
    const size_t ACT = (size_t)MROWS * DIM;          // 8,388,608 elements
    // all intermediates bf16
    unsigned short* y = (unsigned short*)d_ws;
    unsigned short* q = y + ACT;
    unsigned short* k = q + ACT;
    unsigned short* v = k + ACT;
    unsigned short* mid = v + ACT;                   // [32768][1024] bf16 = 4*ACT shorts
    float* ctx = (float*)(mid + 4 * ACT);            // [32][128][48] f32
    float* kmaxf = ctx + (size_t)BH * 128 * 48;
    float* partial = kmaxf + 32;                     // 2048*8 floats
    unsigned short* wt = (unsigned short*)(partial + 2048 * 8);
    unsigned short* o = y;                           // o aliases y (dead between QKV and ln2)

    // per-layer wt stride: 4*(256*256) + 2*(256*1024) = 786432 bf16
    const int WT_L = 786432;
    const int CTXN = BH * 128 * 48;

    copy4_kernel<<<(int)(ACT / 4) / 256, 256, 0, stream>>>((const float4*)x, (float4*)h, (int)(ACT / 4));

    // pre-transpose+convert all weights (all 4 layers)
    wt_kernel<<<dim3(8, 8, 4), 256, 0, stream>>>(Wq, wt + 0, 256, 256, WT_L);
    wt_kernel<<<dim3(8, 8, 4), 256, 0, stream>>>(Wk, wt + 65536, 256, 256, WT_L);
    wt_kernel<<<dim3(8, 8, 4), 256, 0, stream>>>(Wv, wt + 131072, 256, 256, WT_L);
    wt_kernel<<<dim3(8, 8, 4), 256, 0, stream>>>(Wo, wt + 196608, 256, 256, WT_L);
    wt_kernel<<<dim3(8, 32, 4), 256, 0, stream>>>(Wf1, wt + 262144, 256, 1024, WT_L);
    wt_kernel<<<dim3(32, 8, 4), 256, 0, stream>>>(Wf2, wt + 524288, 1024, 256, WT_L);

    for (int i = 0; i < 4; ++i) {
        const float* proj_i = proj + (size_t)i * NB * DHEAD;
        const unsigned short* wl = wt + (size_t)i * WT_L;
        // --- attention ---
        ln_kernel<<<MROWS / 4, 256, 0, stream>>>(h, ln1_g + i * DIM, ln1_b + i * DIM, y);
        dim3 g256(2, 256);
        gemm_mfma<0><<<g256, 256, 0, stream>>>(y, wl + 0, bq + i * INNER, nullptr, q, INNER, DIM);
        gemm_mfma<0><<<g256, 256, 0, stream>>>(y, wl + 65536, bk + i * INNER, nullptr, k, INNER, DIM);
        gemm_mfma<0><<<g256, 256, 0, stream>>>(y, wl + 131072, bv + i * INNER, nullptr, v, INNER, DIM);

        zero_kernel<<<(CTXN + 255) / 256, 256, 0, stream>>>(ctx, CTXN);
        kmaxg_kernel<<<2048, 256, 0, stream>>>(k, proj_i, partial);
        kreduce_kernel<<<BH, 256, 0, stream>>>(partial, kmaxf);
        ctxg_kernel<<<dim3(16, BH), 256, 0, stream>>>(k, v, proj_i, kmaxf, ctx);
        og_kernel<<<BH * 64, 256, 0, stream>>>(q, proj_i, ctx, o);

        gemm_mfma<1><<<g256, 256, 0, stream>>>(o, wl + 196608, bo + i * DIM, h, h, DIM, INNER);

        // --- FFN ---
        ln_kernel<<<MROWS / 4, 256, 0, stream>>>(h, ln2_g + i * DIM, ln2_b + i * DIM, y);
        gemm_mfma<2><<<dim3(8, 256), 256, 0, stream>>>(y, wl + 262144, bf1 + i * FFDIM, nullptr, mid, FFDIM, DIM);
        gemm_mfma<1><<<dim3(2, 256), 256, 0, stream>>>(mid, wl + 524288, bf2 + i * DIM, h, h, DIM, FFDIM);
    }
}